// Round 15
// baseline (1911.051 us; speedup 1.0000x reference)
//
#include <hip/hip_runtime.h>
#include <hip/hip_bf16.h>
#include <math.h>

#define BATCH 4
#define T 1024
#define D 768
#define L 8
#define H 12
#define F 3072
#define V 32000
#define DH 64
#define M (BATCH*T)   // 4096
#define D3 (3*D)      // 2304
#define SCALE 0.125f
#define VCHUNK 6400   // lm_head N-chunk — fallback path
#define PBT 125       // col-partial blocks (32000/256)

typedef unsigned short u16;
typedef __attribute__((ext_vector_type(8))) short bf16x8;
typedef __attribute__((ext_vector_type(4))) float f32x4;

__device__ inline u16 f2b(float f) {
  __hip_bfloat16 h = __float2bfloat16(f);
  return *(u16*)&h;
}

// async global->LDS, 16B per lane; LDS dest is wave-uniform base + lane*16
__device__ inline void gll16(const void* g, void* l) {
  __builtin_amdgcn_global_load_lds(
      (const __attribute__((address_space(1))) unsigned int*)g,
      (__attribute__((address_space(3))) unsigned int*)l, 16, 0, 0);
}

// XOR swizzle for [*][64] u16 LDS tiles (manual-write paths)
__device__ inline int swzi(int r, int c) {
  return (r * 64 + c) ^ ((((r & 7) ^ ((r >> 3) & 7))) << 3);
}

// ---- block-wide reduce (exactly 256 threads / 4 waves) ----
__device__ inline float block_reduce(float v, bool is_max, float* buf4) {
  int lane = threadIdx.x & 63, wid = threadIdx.x >> 6;
#pragma unroll
  for (int off = 32; off; off >>= 1) {
    float o = __shfl_down(v, off, 64);
    v = is_max ? fmaxf(v, o) : v + o;
  }
  if (lane == 0) buf4[wid] = v;
  __syncthreads();
  float r = is_max ? fmaxf(fmaxf(buf4[0], buf4[1]), fmaxf(buf4[2], buf4[3]))
                   : buf4[0] + buf4[1] + buf4[2] + buf4[3];
  __syncthreads();
  return r;
}

// ---- x = tok_emb[idx] + pos_emb ----
__global__ __launch_bounds__(256) void k_embed(const int* __restrict__ idx,
                                               const float* __restrict__ tok,
                                               const float* __restrict__ pos,
                                               float* __restrict__ x) {
  int i = blockIdx.x * 256 + threadIdx.x;
  int row = i / D, d = i - row * D;
  int t = row & (T - 1);
  x[i] = tok[(size_t)idx[row] * D + d] + pos[(size_t)t * D + d];
}

// ---- f32 -> bf16 convert, 4 elems/thread ----
__global__ __launch_bounds__(256) void k_cvt(const float* __restrict__ in,
                                             u16* __restrict__ out, int n4) {
  int i = blockIdx.x * 256 + threadIdx.x;
  if (i >= n4) return;
  float4 v = ((const float4*)in)[i];
  ushort4 o;
  o.x = f2b(v.x); o.y = f2b(v.y); o.z = f2b(v.z); o.w = f2b(v.w);
  ((ushort4*)out)[i] = o;
}

// ---- all block weights f32 -> bf16 in one launch (contiguous dest) ----
__global__ __launch_bounds__(256) void k_cvtw(const float* __restrict__ q,
                                              const float* __restrict__ p,
                                              const float* __restrict__ f1,
                                              const float* __restrict__ f2,
                                              u16* __restrict__ out) {
  const int N0 = L * D3 * D / 4, N1 = L * D * D / 4;
  const int N2 = L * F * D / 4, N3 = L * D * F / 4;
  int i = blockIdx.x * 256 + threadIdx.x;
  if (i >= N0 + N1 + N2 + N3) return;
  const float* src;
  int j = i;
  if (i < N0) { src = q; }
  else if (i < N0 + N1) { src = p; j = i - N0; }
  else if (i < N0 + N1 + N2) { src = f1; j = i - N0 - N1; }
  else { src = f2; j = i - N0 - N1 - N2; }
  float4 v = ((const float4*)src)[j];
  ushort4 o;
  o.x = f2b(v.x); o.y = f2b(v.y); o.z = f2b(v.z); o.w = f2b(v.w);
  ((ushort4*)out)[i] = o;
}

// ---- LayerNorm: one WAVE per row of 768, bf16 out; no LDS, no barriers ----
__global__ __launch_bounds__(256) void k_lnorm(const float* __restrict__ x,
                                               const float* __restrict__ w,
                                               const float* __restrict__ b,
                                               u16* __restrict__ out) {
  int lane = threadIdx.x & 63, wid = threadIdx.x >> 6;
  int row = blockIdx.x * 4 + wid;
  const float4* xr = (const float4*)(x + (size_t)row * D);
  float4 v[3];
  float s = 0.f, ss = 0.f;
#pragma unroll
  for (int p = 0; p < 3; ++p) {
    v[p] = xr[lane + 64 * p];
    s += v[p].x + v[p].y + v[p].z + v[p].w;
    ss += v[p].x * v[p].x + v[p].y * v[p].y + v[p].z * v[p].z + v[p].w * v[p].w;
  }
#pragma unroll
  for (int off = 32; off; off >>= 1) {
    s += __shfl_xor(s, off, 64);
    ss += __shfl_xor(ss, off, 64);
  }
  float mu = s * (1.0f / D);
  float var = ss * (1.0f / D) - mu * mu;
  float rs = rsqrtf(var + 1e-5f);
  ushort4* orow = (ushort4*)(out + (size_t)row * D);
#pragma unroll
  for (int p = 0; p < 3; ++p) {
    float4 wv = ((const float4*)w)[lane + 64 * p];
    float4 bv = ((const float4*)b)[lane + 64 * p];
    ushort4 o;
    o.x = f2b((v[p].x - mu) * rs * wv.x + bv.x);
    o.y = f2b((v[p].y - mu) * rs * wv.y + bv.y);
    o.z = f2b((v[p].z - mu) * rs * wv.z + bv.z);
    o.w = f2b((v[p].w - mu) * rs * wv.w + bv.w);
    orow[lane + 64 * p] = o;
  }
}

// ---- fused: x += sum(4 split-K partials) + bias2; out = LN(x) bf16; x updated ----
__global__ __launch_bounds__(256) void k_lncomb(float* __restrict__ x,
                                                const float* __restrict__ parts,
                                                const float* __restrict__ bias2,
                                                const float* __restrict__ w,
                                                const float* __restrict__ b,
                                                u16* __restrict__ out) {
  int lane = threadIdx.x & 63, wid = threadIdx.x >> 6;
  int row = blockIdx.x * 4 + wid;
  float4* xr = (float4*)(x + (size_t)row * D);
  float4 v[3];
  float s = 0.f, ss = 0.f;
#pragma unroll
  for (int p = 0; p < 3; ++p) {
    v[p] = xr[lane + 64 * p];
#pragma unroll
    for (int pp = 0; pp < 4; ++pp) {
      float4 pv = ((const float4*)(parts + (size_t)pp * M * D + (size_t)row * D))[lane + 64 * p];
      v[p].x += pv.x; v[p].y += pv.y; v[p].z += pv.z; v[p].w += pv.w;
    }
    float4 b2 = ((const float4*)bias2)[lane + 64 * p];
    v[p].x += b2.x; v[p].y += b2.y; v[p].z += b2.z; v[p].w += b2.w;
    s += v[p].x + v[p].y + v[p].z + v[p].w;
    ss += v[p].x * v[p].x + v[p].y * v[p].y + v[p].z * v[p].z + v[p].w * v[p].w;
  }
#pragma unroll
  for (int off = 32; off; off >>= 1) {
    s += __shfl_xor(s, off, 64);
    ss += __shfl_xor(ss, off, 64);
  }
  float mu = s * (1.0f / D);
  float var = ss * (1.0f / D) - mu * mu;
  float rs = rsqrtf(var + 1e-5f);
  ushort4* orow = (ushort4*)(out + (size_t)row * D);
#pragma unroll
  for (int p = 0; p < 3; ++p) {
    xr[lane + 64 * p] = v[p];
    float4 wv = ((const float4*)w)[lane + 64 * p];
    float4 bv = ((const float4*)b)[lane + 64 * p];
    ushort4 o;
    o.x = f2b((v[p].x - mu) * rs * wv.x + bv.x);
    o.y = f2b((v[p].y - mu) * rs * wv.y + bv.y);
    o.z = f2b((v[p].z - mu) * rs * wv.z + bv.z);
    o.w = f2b((v[p].w - mu) * rs * wv.w + bv.w);
    orow[lane + 64 * p] = o;
  }
}

// ---- layer GEMM: C[M,N] = A[M,K] @ W[N,K]^T, 128x128 tile, 8 waves,
//      BK=64 double-buffered, counted vmcnt(4) pipeline, swizzled LDS ----
// flags: 1=bias, 2=residual add (f32), 4=exact gelu, 8=bf16 output,
//        16=split-K partial (f32 out, no bias/resid; K-range = blockIdx.z)
__global__ __launch_bounds__(512, 2) void k_gemm8(
    const u16* __restrict__ A, const u16* __restrict__ W,
    const float* __restrict__ bias, const float* __restrict__ resid,
    void* __restrict__ Cout, int kLen, int kStride, int ldC, int flags) {
  __shared__ __attribute__((aligned(16))) u16 lds[2][2][128 * 64];
  int tid = threadIdx.x, w = tid >> 6, lane = tid & 63;
  int wm = w >> 2, wn = w & 3;
  int bn = blockIdx.x, bm = blockIdx.y;
  int frow = lane & 15, g = lane >> 4;
  int sr = lane >> 3, scu = lane & 7;
  int kz = (flags & 16) ? blockIdx.z * kLen : 0;
  const u16* Ab = A + (size_t)bm * 128 * kStride + kz;
  const u16* Wb = W + (size_t)bn * 128 * kStride + kz;
  float* Cp = (float*)Cout + ((flags & 16) ? (size_t)blockIdx.z * M * (size_t)ldC : 0);
  int NT = kLen >> 6;

  f32x4 acc[4][2];
#pragma unroll
  for (int i = 0; i < 4; ++i)
#pragma unroll
    for (int j = 0; j < 2; ++j) acc[i][j] = (f32x4)(0.f);

#define STG(t)                                                            \
  {                                                                       \
    _Pragma("unroll") for (int rr = 0; rr < 2; ++rr) {                    \
      int row = rr * 64 + w * 8 + sr;                                     \
      int gcu = scu ^ (row & 7);                                          \
      gll16(Ab + (size_t)row * kStride + (t) * 64 + gcu * 8,              \
            &lds[(t) & 1][0][(rr * 64 + w * 8) * 64]);                    \
      gll16(Wb + (size_t)row * kStride + (t) * 64 + gcu * 8,              \
            &lds[(t) & 1][1][(rr * 64 + w * 8) * 64]);                    \
    }                                                                     \
  }

  STG(0);
  asm volatile("s_waitcnt vmcnt(0)");
  __builtin_amdgcn_s_barrier();

  for (int t = 0; t < NT; ++t) {
    if (t + 1 < NT) {
      STG(t + 1);                          // next tile into other buffer
      asm volatile("s_waitcnt vmcnt(4)");  // tile t landed; t+1 stays in flight
    } else {
      asm volatile("s_waitcnt vmcnt(0)");
    }
    __builtin_amdgcn_s_barrier();
    const u16* bA = &lds[t & 1][0][0];
    const u16* bB = &lds[t & 1][1][0];
    bf16x8 ar[8], br[4];
#pragma unroll
    for (int i = 0; i < 4; ++i)
#pragma unroll
      for (int kk = 0; kk < 2; ++kk) {
        int r = wm * 64 + i * 16 + frow;
        ar[i * 2 + kk] = *(const bf16x8*)(bA + r * 64 + ((g + kk * 4) ^ (r & 7)) * 8);
      }
#pragma unroll
    for (int j = 0; j < 2; ++j)
#pragma unroll
      for (int kk = 0; kk < 2; ++kk) {
        int r = wn * 32 + j * 16 + frow;
        br[j * 2 + kk] = *(const bf16x8*)(bB + r * 64 + ((g + kk * 4) ^ (r & 7)) * 8);
      }
    __builtin_amdgcn_s_setprio(1);
#pragma unroll
    for (int i = 0; i < 4; ++i)
#pragma unroll
      for (int j = 0; j < 2; ++j)
#pragma unroll
        for (int kk = 0; kk < 2; ++kk)
          acc[i][j] = __builtin_amdgcn_mfma_f32_16x16x32_bf16(
              ar[i * 2 + kk], br[j * 2 + kk], acc[i][j], 0, 0, 0);
    __builtin_amdgcn_s_setprio(0);
    __builtin_amdgcn_s_barrier();  // reads of buf[t] done before overwrite
  }
#undef STG

  int m0 = bm * 128 + wm * 64 + g * 4;
  int n0 = bn * 128 + wn * 32 + frow;
#pragma unroll
  for (int i = 0; i < 4; ++i) {
#pragma unroll
    for (int j = 0; j < 2; ++j) {
      int n = n0 + j * 16;
      float bv = (flags & 1) ? bias[n] : 0.f;
#pragma unroll
      for (int q = 0; q < 4; ++q) {
        int m = m0 + i * 16 + q;
        size_t off = (size_t)m * ldC + n;
        float v = acc[i][j][q] + bv;
        if (flags & 4) v = 0.5f * v * (1.0f + erff(v * 0.70710678118f));
        if (flags & 2) v += resid[off];
        if (flags & 8) ((u16*)Cout)[off] = f2b(v);
        else           Cp[off] = v;
      }
    }
  }
}

// ---- lm_head 256x256 GEMM, K=768, 8 waves, k_gemm8-style pipeline:
// stage-all-upfront + counted vmcnt(8) + 2 barriers/tile (no per-tile drain).
// Fused per-row LSE partials. Grid (V/256|chunk, M/256), bn fastest.
__global__ __launch_bounds__(512, 2) void k_lm256(
    const u16* __restrict__ A, const u16* __restrict__ B,
    float* __restrict__ C, float* __restrict__ pm, float* __restrict__ ps,
    int gc0) {
  __shared__ __attribute__((aligned(16))) u16 lds[2][2][2][128 * 64];
  __shared__ float pml[256][4], psl[256][4];
  const int K = 768, NT = 12;
  int tid = threadIdx.x, w = tid >> 6, lane = tid & 63;
  int wm = w >> 2, wn = w & 3;
  int bm = blockIdx.y, bn = blockIdx.x;
  int frow = lane & 15, g = lane >> 4;
  int sr = lane >> 3, scu = lane & 7;
  const u16* Abase = A + (size_t)bm * 256 * K;
  const u16* Bbase = B + (size_t)bn * 256 * K;

  f32x4 acc[8][4];
#pragma unroll
  for (int i = 0; i < 8; ++i)
#pragma unroll
    for (int j = 0; j < 4; ++j) acc[i][j] = (f32x4)(0.f);

#define STAGE(t, h)                                                       \
  {                                                                       \
    const u16* src = ((h) < 2 ? Abase : Bbase) + (size_t)(((h)&1) * 128) * K; \
    u16* dst = &lds[(t) & 1][(h) >> 1][(h)&1][0];                         \
    _Pragma("unroll") for (int rr = 0; rr < 2; ++rr) {                    \
      int row = rr * 64 + w * 8 + sr;                                     \
      int gcu = scu ^ (row & 7);                                          \
      gll16(src + (size_t)row * K + (t) * 64 + gcu * 8,                   \
            dst + (rr * 64 + w * 8) * 64);                                \
    }                                                                     \
  }

  bf16x8 ar[8], br[8];
#define LDA(T_, ILO)                                                      \
  {                                                                       \
    const u16* base = &lds[(T_)&1][0][wm][0];                             \
    _Pragma("unroll") for (int ii = 0; ii < 4; ++ii)                      \
    _Pragma("unroll") for (int kk = 0; kk < 2; ++kk) {                    \
      int ri = ((ILO) + ii) * 16 + frow;                                  \
      int u = (g + kk * 4) ^ (ri & 7);                                    \
      ar[ii * 2 + kk] = *(const bf16x8*)(base + ri * 64 + u * 8);         \
    }                                                                     \
  }
#define LDB(T_, JLO, BO)                                                  \
  {                                                                       \
    const u16* base = &lds[(T_)&1][1][wn >> 1][0];                        \
    _Pragma("unroll") for (int jj = 0; jj < 2; ++jj)                      \
    _Pragma("unroll") for (int kk = 0; kk < 2; ++kk) {                    \
      int rj = (wn & 1) * 64 + ((JLO) + jj) * 16 + frow;                  \
      int u = (g + kk * 4) ^ (rj & 7);                                    \
      br[(BO) + jj * 2 + kk] = *(const bf16x8*)(base + rj * 64 + u * 8);  \
    }                                                                     \
  }
#define MFMA16(ILO, JLO, BO)                                              \
  _Pragma("unroll") for (int ii = 0; ii < 4; ++ii)                        \
  _Pragma("unroll") for (int jj = 0; jj < 2; ++jj)                        \
  _Pragma("unroll") for (int kk = 0; kk < 2; ++kk)                        \
    acc[(ILO) + ii][(JLO) + jj] = __builtin_amdgcn_mfma_f32_16x16x32_bf16( \
        ar[ii * 2 + kk], br[(BO) + jj * 2 + kk], acc[(ILO) + ii][(JLO) + jj], 0, 0, 0);

  STAGE(0, 0); STAGE(0, 1); STAGE(0, 2); STAGE(0, 3);
  asm volatile("s_waitcnt vmcnt(0)");
  __builtin_amdgcn_s_barrier();

  for (int t = 0; t < NT; ++t) {
    if (t + 1 < NT) {
      // stage all of tile t+1 into the other buffer; counted wait keeps
      // its 8 loads in flight while tile t computes (T4)
      STAGE(t + 1, 0); STAGE(t + 1, 1); STAGE(t + 1, 2); STAGE(t + 1, 3);
      asm volatile("s_waitcnt vmcnt(8)");
    } else {
      asm volatile("s_waitcnt vmcnt(0)");
    }
    __builtin_amdgcn_s_barrier();
    // compute tile t, barrier-free (staging writes the other buffer)
    LDA(t, 0); LDB(t, 0, 0); LDB(t, 2, 4);
    __builtin_amdgcn_s_setprio(1);
    MFMA16(0, 0, 0);
    MFMA16(0, 2, 4);
    __builtin_amdgcn_s_setprio(0);
    LDA(t, 4);
    __builtin_amdgcn_s_setprio(1);
    MFMA16(4, 0, 0);
    MFMA16(4, 2, 4);
    __builtin_amdgcn_s_setprio(0);
    __builtin_amdgcn_s_barrier();  // reads of buf[t] done before overwrite
  }

#pragma unroll
  for (int ii = 0; ii < 8; ++ii) {
#pragma unroll
    for (int q = 0; q < 4; ++q) {
      float mx = fmaxf(fmaxf(acc[ii][0][q], acc[ii][1][q]),
                       fmaxf(acc[ii][2][q], acc[ii][3][q]));
      mx = fmaxf(mx, __shfl_xor(mx, 1, 64));
      mx = fmaxf(mx, __shfl_xor(mx, 2, 64));
      mx = fmaxf(mx, __shfl_xor(mx, 4, 64));
      mx = fmaxf(mx, __shfl_xor(mx, 8, 64));
      float sm = 0.f;
#pragma unroll
      for (int jj = 0; jj < 4; ++jj) sm += __expf(acc[ii][jj][q] - mx);
      sm += __shfl_xor(sm, 1, 64);
      sm += __shfl_xor(sm, 2, 64);
      sm += __shfl_xor(sm, 4, 64);
      sm += __shfl_xor(sm, 8, 64);
      int lrow = wm * 128 + ii * 16 + g * 4 + q;
      if (frow == 0) { pml[lrow][wn] = mx; psl[lrow][wn] = sm; }
      size_t off = (size_t)(bm * 256 + lrow) * V + gc0 + bn * 256 + wn * 64 + frow;
#pragma unroll
      for (int jj = 0; jj < 4; ++jj) C[off + jj * 16] = acc[ii][jj][q];
    }
  }
  __syncthreads();
  if (tid < 256) {
    float m = fmaxf(fmaxf(pml[tid][0], pml[tid][1]), fmaxf(pml[tid][2], pml[tid][3]));
    float s = 0.f;
#pragma unroll
    for (int w4 = 0; w4 < 4; ++w4) s += psl[tid][w4] * __expf(pml[tid][w4] - m);
    size_t grow = bm * 256 + tid;
    int pb = gc0 / 256 + bn;
    pm[grow * PBT + pb] = m;
    ps[grow * PBT + pb] = s;
  }
#undef STAGE
#undef LDA
#undef LDB
#undef MFMA16
}

// ---- MFMA flash attention, balanced + 8-wave parallel pair ----
__global__ __launch_bounds__(512) void k_fattn(const u16* __restrict__ qkv,
                                               u16* __restrict__ y) {
  __shared__ __attribute__((aligned(16))) u16 lQ[2][64 * 64];
  __shared__ __attribute__((aligned(16))) u16 lK[64 * 64];
  __shared__ __attribute__((aligned(16))) u16 lVt[64 * 64];
  __shared__ __attribute__((aligned(16))) u16 lP[128 * 64];
  int tid = threadIdx.x;
  int w = tid >> 6, lane = tid & 63;
  int tq = w >> 2, ws4 = w & 3;
  int xi = blockIdx.x;
  int bh = blockIdx.y, b = bh / H, h = bh - b * H;
  int myqt = tq ? xi : (15 - xi);
  const u16* base = qkv + (size_t)b * T * D3 + h * DH;
  int srow = lane >> 3;
  int scu = lane & 7;
  int frow = lane & 15, g = lane >> 4;
  int s16 = ws4 * 16;
  int qrow = g * 4;
  int f7 = frow & 7;

#pragma unroll
  for (int c = 0; c < 2; ++c) {
    int row = s16 + c * 8 + srow;
    int gcu = scu ^ (row & 7);
    gll16(base + (size_t)(myqt * 64 + row) * D3 + gcu * 8,
          &lQ[tq][(s16 + c * 8) * 64]);
  }

  float m_r[4], l_r[4];
  f32x4 o[4];
#pragma unroll
  for (int i = 0; i < 4; ++i) { m_r[i] = -1e30f; l_r[i] = 0.f; o[i] = (f32x4)(0.f); }

  int ktmax = 15 - xi;
  int kvrow = w * 8 + srow;
  uint4 kr = *(const uint4*)(base + D + (size_t)kvrow * D3 + scu * 8);
  uint4 vr = *(const uint4*)(base + 2 * D + (size_t)kvrow * D3 + scu * 8);

  for (int kt = 0; kt <= ktmax; ++kt) {
    __syncthreads();
    int k0 = kt * 64;
    *(uint4*)(lK + kvrow * 64 + (scu ^ (kvrow & 7)) * 8) = kr;
    {
      unsigned vals[4] = {vr.x, vr.y, vr.z, vr.w};
#pragma unroll
      for (int e = 0; e < 4; ++e) {
        lVt[swzi(scu * 8 + 2 * e, kvrow)]     = (u16)(vals[e] & 0xffff);
        lVt[swzi(scu * 8 + 2 * e + 1, kvrow)] = (u16)(vals[e] >> 16);
      }
    }
    __syncthreads();
    if (kt < ktmax) {
      int rown = k0 + 64 + kvrow;
      kr = *(const uint4*)(base + D + (size_t)rown * D3 + scu * 8);
      vr = *(const uint4*)(base + 2 * D + (size_t)rown * D3 + scu * 8);
    }

    if (tq == 0 || kt <= xi) {
      bool diag = (kt == myqt);
      const u16* lq = &lQ[tq][0];
      bf16x8 aq0 = *(const bf16x8*)(lq + (s16 + frow) * 64 + (g ^ f7) * 8);
      bf16x8 aq1 = *(const bf16x8*)(lq + (s16 + frow) * 64 + ((g + 4) ^ f7) * 8);
      f32x4 sv[4];
#pragma unroll
      for (int kn = 0; kn < 4; ++kn) {
        bf16x8 bk0 = *(const bf16x8*)(lK + (kn * 16 + frow) * 64 + (g ^ f7) * 8);
        bf16x8 bk1 = *(const bf16x8*)(lK + (kn * 16 + frow) * 64 + ((g + 4) ^ f7) * 8);
        sv[kn] = __builtin_amdgcn_mfma_f32_16x16x32_bf16(aq0, bk0, (f32x4)(0.f), 0, 0, 0);
        sv[kn] = __builtin_amdgcn_mfma_f32_16x16x32_bf16(aq1, bk1, sv[kn], 0, 0, 0);
      }
#pragma unroll
      for (int kn = 0; kn < 4; ++kn)
#pragma unroll
        for (int qi = 0; qi < 4; ++qi) {
          float v = sv[kn][qi] * SCALE;
          if (diag) {
            int qg = myqt * 64 + s16 + qrow + qi;
            int kg = k0 + kn * 16 + frow;
            if (kg > qg) v = -1e30f;
          }
          sv[kn][qi] = v;
        }
#pragma unroll
      for (int qi = 0; qi < 4; ++qi) {
        float rm = fmaxf(fmaxf(sv[0][qi], sv[1][qi]), fmaxf(sv[2][qi], sv[3][qi]));
        rm = fmaxf(rm, __shfl_xor(rm, 1, 64));
        rm = fmaxf(rm, __shfl_xor(rm, 2, 64));
        rm = fmaxf(rm, __shfl_xor(rm, 4, 64));
        rm = fmaxf(rm, __shfl_xor(rm, 8, 64));
        float mn = fmaxf(m_r[qi], rm);
        float alpha = __expf(m_r[qi] - mn);
        m_r[qi] = mn;
        float rs = 0.f;
#pragma unroll
        for (int kn = 0; kn < 4; ++kn) {
          float p = __expf(sv[kn][qi] - mn);
          sv[kn][qi] = p;
          rs += p;
        }
        rs += __shfl_xor(rs, 1, 64);
        rs += __shfl_xor(rs, 2, 64);
        rs += __shfl_xor(rs, 4, 64);
        rs += __shfl_xor(rs, 8, 64);
        l_r[qi] = l_r[qi] * alpha + rs;
#pragma unroll
        for (int df = 0; df < 4; ++df) o[df][qi] *= alpha;
      }
#pragma unroll
      for (int kn = 0; kn < 4; ++kn)
#pragma unroll
        for (int qi = 0; qi < 4; ++qi)
          lP[swzi(w * 16 + qrow + qi, kn * 16 + frow)] = f2b(sv[kn][qi]);
      bf16x8 pa0 = *(const bf16x8*)(lP + swzi(w * 16 + frow, g * 8));
      bf16x8 pa1 = *(const bf16x8*)(lP + swzi(w * 16 + frow, 32 + g * 8));
#pragma unroll
      for (int df = 0; df < 4; ++df) {
        bf16x8 bv0 = *(const bf16x8*)(lVt + swzi(df * 16 + frow, g * 8));
        bf16x8 bv1 = *(const bf16x8*)(lVt + swzi(df * 16 + frow, 32 + g * 8));
        o[df] = __builtin_amdgcn_mfma_f32_16x16x32_bf16(pa0, bv0, o[df], 0, 0, 0);
        o[df] = __builtin_amdgcn_mfma_f32_16x16x32_bf16(pa1, bv1, o[df], 0, 0, 0);
      }
    }
  }

#pragma unroll
  for (int df = 0; df < 4; ++df)
#pragma unroll
    for (int qi = 0; qi < 4; ++qi) {
      int qg = myqt * 64 + s16 + qrow + qi;
      y[(size_t)(b * T + qg) * D + h * DH + df * 16 + frow] =
          f2b(o[df][qi] / l_r[qi]);
    }
}

// ---- final LSE + NLL from partials; one wave per row ----
__global__ __launch_bounds__(256) void k_loss_rows(
    const float* __restrict__ pm, const float* __restrict__ ps,
    const float* __restrict__ logits, const int* __restrict__ targets,
    float* __restrict__ nll) {
  int lane = threadIdx.x & 63, wid = threadIdx.x >> 6;
  int row = blockIdx.x * 4 + wid;
  const float* pmr = pm + (size_t)row * PBT;
  const float* psr = ps + (size_t)row * PBT;
  float m = -1e30f;
  for (int i = lane; i < PBT; i += 64) m = fmaxf(m, pmr[i]);
#pragma unroll
  for (int off = 32; off; off >>= 1) m = fmaxf(m, __shfl_xor(m, off, 64));
  float s = 0.f;
  for (int i = lane; i < PBT; i += 64) s += psr[i] * __expf(pmr[i] - m);
#pragma unroll
  for (int off = 32; off; off >>= 1) s += __shfl_xor(s, off, 64);
  if (lane == 0) {
    int tgt = targets[row];
    nll[row] = (tgt != -100) ? (m + logf(s) - logits[(size_t)row * V + tgt]) : 0.f;
  }
}

__global__ __launch_bounds__(256) void k_loss_final(const float* __restrict__ nll,
                                                    const int* __restrict__ targets,
                                                    float* __restrict__ out) {
  __shared__ float buf4[4];
  float s = 0.f, c = 0.f;
  for (int i = threadIdx.x; i < M; i += 256) {
    s += nll[i];
    c += (targets[i] != -100) ? 1.f : 0.f;
  }
  s = block_reduce(s, false, buf4);
  c = block_reduce(c, false, buf4);
  if (threadIdx.x == 0) out[0] = s / fmaxf(c, 1.f);
}

extern "C" void kernel_launch(void* const* d_in, const int* in_sizes, int n_in,
                              void* d_out, int out_size, void* d_ws, size_t ws_size,
                              hipStream_t stream) {
  const int* idx       = (const int*)d_in[0];
  const int* targets   = (const int*)d_in[1];
  const float* tok     = (const float*)d_in[2];
  const float* pos     = (const float*)d_in[3];
  const float* qkv_w   = (const float*)d_in[4];
  const float* qkv_b   = (const float*)d_in[5];
  const float* proj_w  = (const float*)d_in[6];
  const float* proj_b  = (const float*)d_in[7];
  const float* fc1_w   = (const float*)d_in[8];
  const float* fc1_b   = (const float*)d_in[9];
  const float* fc2_w   = (const float*)d_in[10];
  const float* fc2_b   = (const float*)d_in[11];
  const float* ln1_w   = (const float*)d_in[12];
  const float* ln1_b   = (const float*)d_in[13];
  const float* ln2_w   = (const float*)d_in[14];
  const float* ln2_b   = (const float*)d_in[15];
  const float* lnf_w   = (const float*)d_in[16];
  const float* lnf_b   = (const float*)d_in[17];

  float* logits = (float*)d_out;

  // ---- ws layout ----
  char* ws = (char*)d_ws;
  float* x   = (float*)ws;                  // M*D f32        12.58 MB
  u16* hb    = (u16*)(ws + 12582912);       // M*D bf16        6.29 MB
  u16* yb    = (u16*)(ws + 18874368);       // M*D bf16        6.29 MB
  u16* wb    = (u16*)(ws + 25165824);       // lm_head B bf16 (chunk or full tok)
  bool big = ws_size >= (size_t)(25165824 + 49152000 + 2048000 * 2 + 16384);
  float* pm, * ps, * nll;
  if (big) {
    pm  = (float*)(ws + 25165824 + 49152000);
    ps  = (float*)(ws + 25165824 + 49152000 + 2048000);
    nll = (float*)(ws + 25165824 + 49152000 + 4096000);
  } else {
    pm  = (float*)(ws + 34996224);
    ps  = (float*)(ws + 37044224);
    nll = (float*)(ws + 39092224);
  }

  // ---- d_out scratch (dead before logits are written) ----
  u16* qkvb   = (u16*)logits;                        // M*D3 bf16
  u16* f1b    = (u16*)(logits + 9437184);            // M*F bf16
  u16* wqkv   = (u16*)(logits + 15728640);           // contiguous weights (ends ~176MB)
  u16* wproj  = (u16*)(logits + 22806528);
  u16* wfc1   = (u16*)(logits + 25165824);
  u16* wfc2   = (u16*)(logits + 34603008);
  float* fc2p = (float*)((char*)logits + 201326592); // 4x M*D f32 split-K partials

  {
    const int NW4 = (L * D3 * D + L * D * D + L * F * D + L * D * F) / 4;
    k_cvtw<<<(NW4 + 255) / 256, 256, 0, stream>>>(qkv_w, proj_w, fc1_w, fc2_w, wqkv);
  }

  k_embed<<<(M * D) / 256, 256, 0, stream>>>(idx, tok, pos, x);

  for (int l = 0; l < L; ++l) {
    if (l == 0)
      k_lnorm<<<M / 4, 256, 0, stream>>>(x, ln1_w, ln1_b, hb);
    else
      k_lncomb<<<M / 4, 256, 0, stream>>>(x, fc2p, fc2_b + (size_t)(l - 1) * D,
                                          ln1_w + (size_t)l * D, ln1_b + (size_t)l * D, hb);
    k_gemm8<<<dim3(D3 / 128, M / 128), 512, 0, stream>>>(
        hb, wqkv + (size_t)l * D3 * D, qkv_b + (size_t)l * D3, nullptr, qkvb, D, D, D3, 9);
    k_fattn<<<dim3(8, BATCH * H), 512, 0, stream>>>(qkvb, yb);
    k_gemm8<<<dim3(D / 128, M / 128), 512, 0, stream>>>(
        yb, wproj + (size_t)l * D * D, proj_b + (size_t)l * D, x, x, D, D, D, 3);
    k_lnorm<<<M / 4, 256, 0, stream>>>(x, ln2_w + (size_t)l * D, ln2_b + (size_t)l * D, hb);
    k_gemm8<<<dim3(F / 128, M / 128), 512, 0, stream>>>(
        hb, wfc1 + (size_t)l * F * D, fc1_b + (size_t)l * F, nullptr, f1b, D, D, F, 13);
    // fc2 split-K=4: partials only; combine fused into next LN
    k_gemm8<<<dim3(D / 128, M / 128, 4), 512, 0, stream>>>(
        f1b, wfc2 + (size_t)l * D * F, nullptr, nullptr, fc2p, 768, F, D, 16);
  }

  k_lncomb<<<M / 4, 256, 0, stream>>>(x, fc2p, fc2_b + (size_t)(L - 1) * D,
                                      lnf_w, lnf_b, hb);
  if (big) {
    k_cvt<<<(V * D / 4 + 255) / 256, 256, 0, stream>>>(tok, wb, V * D / 4);
    k_lm256<<<dim3(V / 256, M / 256), 512, 0, stream>>>(
        hb, wb, logits, pm, ps, 0);
  } else {
    for (int c = 0; c < 5; ++c) {
      k_cvt<<<(VCHUNK * D / 4 + 255) / 256, 256, 0, stream>>>(
          tok + (size_t)c * VCHUNK * D, wb, VCHUNK * D / 4);
      k_lm256<<<dim3(VCHUNK / 256, M / 256), 512, 0, stream>>>(
          hb, wb, logits, pm, ps, c * VCHUNK);
    }
  }
  k_loss_rows<<<M / 4, 256, 0, stream>>>(pm, ps, logits, targets, nll);
  k_loss_final<<<1, 256, 0, stream>>>(nll, targets, logits + (size_t)M * V);
}

// Round 16
// 1898.442 us; speedup vs baseline: 1.0066x; 1.0066x over previous
//
#include <hip/hip_runtime.h>
#include <hip/hip_bf16.h>
#include <math.h>

#define BATCH 4
#define T 1024
#define D 768
#define L 8
#define H 12
#define F 3072
#define V 32000
#define DH 64
#define M (BATCH*T)   // 4096
#define D3 (3*D)      // 2304
#define SCALE 0.125f
#define VCHUNK 6400   // lm_head N-chunk — fallback path
#define PBT 125       // col-partial blocks (32000/256)

typedef unsigned short u16;
typedef __attribute__((ext_vector_type(8))) short bf16x8;
typedef __attribute__((ext_vector_type(4))) float f32x4;

__device__ inline u16 f2b(float f) {
  __hip_bfloat16 h = __float2bfloat16(f);
  return *(u16*)&h;
}

// async global->LDS, 16B per lane; LDS dest is wave-uniform base + lane*16
__device__ inline void gll16(const void* g, void* l) {
  __builtin_amdgcn_global_load_lds(
      (const __attribute__((address_space(1))) unsigned int*)g,
      (__attribute__((address_space(3))) unsigned int*)l, 16, 0, 0);
}

// XOR swizzle for [*][64] u16 LDS tiles (manual-write paths)
__device__ inline int swzi(int r, int c) {
  return (r * 64 + c) ^ ((((r & 7) ^ ((r >> 3) & 7))) << 3);
}

// ---- block-wide reduce (exactly 256 threads / 4 waves) ----
__device__ inline float block_reduce(float v, bool is_max, float* buf4) {
  int lane = threadIdx.x & 63, wid = threadIdx.x >> 6;
#pragma unroll
  for (int off = 32; off; off >>= 1) {
    float o = __shfl_down(v, off, 64);
    v = is_max ? fmaxf(v, o) : v + o;
  }
  if (lane == 0) buf4[wid] = v;
  __syncthreads();
  float r = is_max ? fmaxf(fmaxf(buf4[0], buf4[1]), fmaxf(buf4[2], buf4[3]))
                   : buf4[0] + buf4[1] + buf4[2] + buf4[3];
  __syncthreads();
  return r;
}

// ---- x = tok_emb[idx] + pos_emb ----
__global__ __launch_bounds__(256) void k_embed(const int* __restrict__ idx,
                                               const float* __restrict__ tok,
                                               const float* __restrict__ pos,
                                               float* __restrict__ x) {
  int i = blockIdx.x * 256 + threadIdx.x;
  int row = i / D, d = i - row * D;
  int t = row & (T - 1);
  x[i] = tok[(size_t)idx[row] * D + d] + pos[(size_t)t * D + d];
}

// ---- f32 -> bf16 convert, 4 elems/thread ----
__global__ __launch_bounds__(256) void k_cvt(const float* __restrict__ in,
                                             u16* __restrict__ out, int n4) {
  int i = blockIdx.x * 256 + threadIdx.x;
  if (i >= n4) return;
  float4 v = ((const float4*)in)[i];
  ushort4 o;
  o.x = f2b(v.x); o.y = f2b(v.y); o.z = f2b(v.z); o.w = f2b(v.w);
  ((ushort4*)out)[i] = o;
}

// ---- all block weights f32 -> bf16 in one launch (contiguous dest) ----
__global__ __launch_bounds__(256) void k_cvtw(const float* __restrict__ q,
                                              const float* __restrict__ p,
                                              const float* __restrict__ f1,
                                              const float* __restrict__ f2,
                                              u16* __restrict__ out) {
  const int N0 = L * D3 * D / 4, N1 = L * D * D / 4;
  const int N2 = L * F * D / 4, N3 = L * D * F / 4;
  int i = blockIdx.x * 256 + threadIdx.x;
  if (i >= N0 + N1 + N2 + N3) return;
  const float* src;
  int j = i;
  if (i < N0) { src = q; }
  else if (i < N0 + N1) { src = p; j = i - N0; }
  else if (i < N0 + N1 + N2) { src = f1; j = i - N0 - N1; }
  else { src = f2; j = i - N0 - N1 - N2; }
  float4 v = ((const float4*)src)[j];
  ushort4 o;
  o.x = f2b(v.x); o.y = f2b(v.y); o.z = f2b(v.z); o.w = f2b(v.w);
  ((ushort4*)out)[i] = o;
}

// ---- LayerNorm: one WAVE per row of 768, bf16 out; no LDS, no barriers ----
__global__ __launch_bounds__(256) void k_lnorm(const float* __restrict__ x,
                                               const float* __restrict__ w,
                                               const float* __restrict__ b,
                                               u16* __restrict__ out) {
  int lane = threadIdx.x & 63, wid = threadIdx.x >> 6;
  int row = blockIdx.x * 4 + wid;
  const float4* xr = (const float4*)(x + (size_t)row * D);
  float4 v[3];
  float s = 0.f, ss = 0.f;
#pragma unroll
  for (int p = 0; p < 3; ++p) {
    v[p] = xr[lane + 64 * p];
    s += v[p].x + v[p].y + v[p].z + v[p].w;
    ss += v[p].x * v[p].x + v[p].y * v[p].y + v[p].z * v[p].z + v[p].w * v[p].w;
  }
#pragma unroll
  for (int off = 32; off; off >>= 1) {
    s += __shfl_xor(s, off, 64);
    ss += __shfl_xor(ss, off, 64);
  }
  float mu = s * (1.0f / D);
  float var = ss * (1.0f / D) - mu * mu;
  float rs = rsqrtf(var + 1e-5f);
  ushort4* orow = (ushort4*)(out + (size_t)row * D);
#pragma unroll
  for (int p = 0; p < 3; ++p) {
    float4 wv = ((const float4*)w)[lane + 64 * p];
    float4 bv = ((const float4*)b)[lane + 64 * p];
    ushort4 o;
    o.x = f2b((v[p].x - mu) * rs * wv.x + bv.x);
    o.y = f2b((v[p].y - mu) * rs * wv.y + bv.y);
    o.z = f2b((v[p].z - mu) * rs * wv.z + bv.z);
    o.w = f2b((v[p].w - mu) * rs * wv.w + bv.w);
    orow[lane + 64 * p] = o;
  }
}

// ---- fused: x += sum(4 split-K partials) + bias2; out = LN(x) bf16; x updated ----
__global__ __launch_bounds__(256) void k_lncomb(float* __restrict__ x,
                                                const float* __restrict__ parts,
                                                const float* __restrict__ bias2,
                                                const float* __restrict__ w,
                                                const float* __restrict__ b,
                                                u16* __restrict__ out) {
  int lane = threadIdx.x & 63, wid = threadIdx.x >> 6;
  int row = blockIdx.x * 4 + wid;
  float4* xr = (float4*)(x + (size_t)row * D);
  float4 v[3];
  float s = 0.f, ss = 0.f;
#pragma unroll
  for (int p = 0; p < 3; ++p) {
    v[p] = xr[lane + 64 * p];
#pragma unroll
    for (int pp = 0; pp < 4; ++pp) {
      float4 pv = ((const float4*)(parts + (size_t)pp * M * D + (size_t)row * D))[lane + 64 * p];
      v[p].x += pv.x; v[p].y += pv.y; v[p].z += pv.z; v[p].w += pv.w;
    }
    float4 b2 = ((const float4*)bias2)[lane + 64 * p];
    v[p].x += b2.x; v[p].y += b2.y; v[p].z += b2.z; v[p].w += b2.w;
    s += v[p].x + v[p].y + v[p].z + v[p].w;
    ss += v[p].x * v[p].x + v[p].y * v[p].y + v[p].z * v[p].z + v[p].w * v[p].w;
  }
#pragma unroll
  for (int off = 32; off; off >>= 1) {
    s += __shfl_xor(s, off, 64);
    ss += __shfl_xor(ss, off, 64);
  }
  float mu = s * (1.0f / D);
  float var = ss * (1.0f / D) - mu * mu;
  float rs = rsqrtf(var + 1e-5f);
  ushort4* orow = (ushort4*)(out + (size_t)row * D);
#pragma unroll
  for (int p = 0; p < 3; ++p) {
    xr[lane + 64 * p] = v[p];
    float4 wv = ((const float4*)w)[lane + 64 * p];
    float4 bv = ((const float4*)b)[lane + 64 * p];
    ushort4 o;
    o.x = f2b((v[p].x - mu) * rs * wv.x + bv.x);
    o.y = f2b((v[p].y - mu) * rs * wv.y + bv.y);
    o.z = f2b((v[p].z - mu) * rs * wv.z + bv.z);
    o.w = f2b((v[p].w - mu) * rs * wv.w + bv.w);
    orow[lane + 64 * p] = o;
  }
}

// ---- layer GEMM: C[M,N] = A[M,K] @ W[N,K]^T, 128x128 tile, 8 waves,
//      BK=64 double-buffered, counted vmcnt(4) pipeline, swizzled LDS ----
// flags: 1=bias, 2=residual add (f32), 4=exact gelu, 8=bf16 output,
//        16=split-K partial (f32 out, no bias/resid; K-range = blockIdx.z)
__global__ __launch_bounds__(512, 2) void k_gemm8(
    const u16* __restrict__ A, const u16* __restrict__ W,
    const float* __restrict__ bias, const float* __restrict__ resid,
    void* __restrict__ Cout, int kLen, int kStride, int ldC, int flags) {
  __shared__ __attribute__((aligned(16))) u16 lds[2][2][128 * 64];
  int tid = threadIdx.x, w = tid >> 6, lane = tid & 63;
  int wm = w >> 2, wn = w & 3;
  int bn = blockIdx.x, bm = blockIdx.y;
  int frow = lane & 15, g = lane >> 4;
  int sr = lane >> 3, scu = lane & 7;
  int kz = (flags & 16) ? blockIdx.z * kLen : 0;
  const u16* Ab = A + (size_t)bm * 128 * kStride + kz;
  const u16* Wb = W + (size_t)bn * 128 * kStride + kz;
  float* Cp = (float*)Cout + ((flags & 16) ? (size_t)blockIdx.z * M * (size_t)ldC : 0);
  int NT = kLen >> 6;

  f32x4 acc[4][2];
#pragma unroll
  for (int i = 0; i < 4; ++i)
#pragma unroll
    for (int j = 0; j < 2; ++j) acc[i][j] = (f32x4)(0.f);

#define STG(t)                                                            \
  {                                                                       \
    _Pragma("unroll") for (int rr = 0; rr < 2; ++rr) {                    \
      int row = rr * 64 + w * 8 + sr;                                     \
      int gcu = scu ^ (row & 7);                                          \
      gll16(Ab + (size_t)row * kStride + (t) * 64 + gcu * 8,              \
            &lds[(t) & 1][0][(rr * 64 + w * 8) * 64]);                    \
      gll16(Wb + (size_t)row * kStride + (t) * 64 + gcu * 8,              \
            &lds[(t) & 1][1][(rr * 64 + w * 8) * 64]);                    \
    }                                                                     \
  }

  STG(0);
  asm volatile("s_waitcnt vmcnt(0)");
  __builtin_amdgcn_s_barrier();

  for (int t = 0; t < NT; ++t) {
    if (t + 1 < NT) {
      STG(t + 1);                          // next tile into other buffer
      asm volatile("s_waitcnt vmcnt(4)");  // tile t landed; t+1 stays in flight
    } else {
      asm volatile("s_waitcnt vmcnt(0)");
    }
    __builtin_amdgcn_s_barrier();
    const u16* bA = &lds[t & 1][0][0];
    const u16* bB = &lds[t & 1][1][0];
    bf16x8 ar[8], br[4];
#pragma unroll
    for (int i = 0; i < 4; ++i)
#pragma unroll
      for (int kk = 0; kk < 2; ++kk) {
        int r = wm * 64 + i * 16 + frow;
        ar[i * 2 + kk] = *(const bf16x8*)(bA + r * 64 + ((g + kk * 4) ^ (r & 7)) * 8);
      }
#pragma unroll
    for (int j = 0; j < 2; ++j)
#pragma unroll
      for (int kk = 0; kk < 2; ++kk) {
        int r = wn * 32 + j * 16 + frow;
        br[j * 2 + kk] = *(const bf16x8*)(bB + r * 64 + ((g + kk * 4) ^ (r & 7)) * 8);
      }
    __builtin_amdgcn_s_setprio(1);
#pragma unroll
    for (int i = 0; i < 4; ++i)
#pragma unroll
      for (int j = 0; j < 2; ++j)
#pragma unroll
        for (int kk = 0; kk < 2; ++kk)
          acc[i][j] = __builtin_amdgcn_mfma_f32_16x16x32_bf16(
              ar[i * 2 + kk], br[j * 2 + kk], acc[i][j], 0, 0, 0);
    __builtin_amdgcn_s_setprio(0);
    __builtin_amdgcn_s_barrier();  // reads of buf[t] done before overwrite
  }
#undef STG

  int m0 = bm * 128 + wm * 64 + g * 4;
  int n0 = bn * 128 + wn * 32 + frow;
#pragma unroll
  for (int i = 0; i < 4; ++i) {
#pragma unroll
    for (int j = 0; j < 2; ++j) {
      int n = n0 + j * 16;
      float bv = (flags & 1) ? bias[n] : 0.f;
#pragma unroll
      for (int q = 0; q < 4; ++q) {
        int m = m0 + i * 16 + q;
        size_t off = (size_t)m * ldC + n;
        float v = acc[i][j][q] + bv;
        if (flags & 4) v = 0.5f * v * (1.0f + erff(v * 0.70710678118f));
        if (flags & 2) v += resid[off];
        if (flags & 8) ((u16*)Cout)[off] = f2b(v);
        else           Cp[off] = v;
      }
    }
  }
}

// ---- lm_head 256x256 GEMM, K=768 fixed, 8 waves, dbuf + 4-phase + fused LSE.
// Round-14 proven schedule: next-tile stages issued in phases A/B, single
// vmcnt(0) drain at phase D waits on >=2-phase-old loads. 308 us measured.
__global__ __launch_bounds__(512, 2) void k_lm256(
    const u16* __restrict__ A, const u16* __restrict__ B,
    float* __restrict__ C, float* __restrict__ pm, float* __restrict__ ps,
    int gc0) {
  __shared__ __attribute__((aligned(16))) u16 lds[2][2][2][128 * 64];
  __shared__ float pml[256][4], psl[256][4];
  const int K = 768, NT = 12;
  int tid = threadIdx.x, w = tid >> 6, lane = tid & 63;
  int wm = w >> 2, wn = w & 3;
  int bm = blockIdx.y, bn = blockIdx.x;
  int frow = lane & 15, g = lane >> 4;
  int sr = lane >> 3, scu = lane & 7;
  const u16* Abase = A + (size_t)bm * 256 * K;
  const u16* Bbase = B + (size_t)bn * 256 * K;

  f32x4 acc[8][4];
#pragma unroll
  for (int i = 0; i < 8; ++i)
#pragma unroll
    for (int j = 0; j < 4; ++j) acc[i][j] = (f32x4)(0.f);

#define STAGE(t, h)                                                       \
  {                                                                       \
    const u16* src = ((h) < 2 ? Abase : Bbase) + (size_t)(((h)&1) * 128) * K; \
    u16* dst = &lds[(t) & 1][(h) >> 1][(h)&1][0];                         \
    _Pragma("unroll") for (int rr = 0; rr < 2; ++rr) {                    \
      int row = rr * 64 + w * 8 + sr;                                     \
      int gcu = scu ^ (row & 7);                                          \
      gll16(src + (size_t)row * K + (t) * 64 + gcu * 8,                   \
            dst + (rr * 64 + w * 8) * 64);                                \
    }                                                                     \
  }

  bf16x8 ar[8], br[8];
#define LDA(T_, ILO)                                                      \
  {                                                                       \
    const u16* base = &lds[(T_)&1][0][wm][0];                             \
    _Pragma("unroll") for (int ii = 0; ii < 4; ++ii)                      \
    _Pragma("unroll") for (int kk = 0; kk < 2; ++kk) {                    \
      int ri = ((ILO) + ii) * 16 + frow;                                  \
      int u = (g + kk * 4) ^ (ri & 7);                                    \
      ar[ii * 2 + kk] = *(const bf16x8*)(base + ri * 64 + u * 8);         \
    }                                                                     \
  }
#define LDB(T_, JLO, BO)                                                  \
  {                                                                       \
    const u16* base = &lds[(T_)&1][1][wn >> 1][0];                        \
    _Pragma("unroll") for (int jj = 0; jj < 2; ++jj)                      \
    _Pragma("unroll") for (int kk = 0; kk < 2; ++kk) {                    \
      int rj = (wn & 1) * 64 + ((JLO) + jj) * 16 + frow;                  \
      int u = (g + kk * 4) ^ (rj & 7);                                    \
      br[(BO) + jj * 2 + kk] = *(const bf16x8*)(base + rj * 64 + u * 8);  \
    }                                                                     \
  }
#define MFMA16(ILO, JLO, BO)                                              \
  _Pragma("unroll") for (int ii = 0; ii < 4; ++ii)                        \
  _Pragma("unroll") for (int jj = 0; jj < 2; ++jj)                        \
  _Pragma("unroll") for (int kk = 0; kk < 2; ++kk)                        \
    acc[(ILO) + ii][(JLO) + jj] = __builtin_amdgcn_mfma_f32_16x16x32_bf16( \
        ar[ii * 2 + kk], br[(BO) + jj * 2 + kk], acc[(ILO) + ii][(JLO) + jj], 0, 0, 0);

  STAGE(0, 0); STAGE(0, 1); STAGE(0, 2); STAGE(0, 3);
  asm volatile("s_waitcnt vmcnt(0)");
  __builtin_amdgcn_s_barrier();

  for (int t = 0; t < NT; ++t) {
    bool pf = (t + 1 < NT);
    LDA(t, 0); LDB(t, 0, 0);
    if (pf) { STAGE(t + 1, 0); STAGE(t + 1, 1); }
    __builtin_amdgcn_s_setprio(1);
    MFMA16(0, 0, 0);
    __builtin_amdgcn_s_setprio(0);
    __builtin_amdgcn_s_barrier();
    LDB(t, 2, 4);
    if (pf) { STAGE(t + 1, 2); STAGE(t + 1, 3); }
    __builtin_amdgcn_s_setprio(1);
    MFMA16(0, 2, 4);
    __builtin_amdgcn_s_setprio(0);
    __builtin_amdgcn_s_barrier();
    LDA(t, 4);
    __builtin_amdgcn_s_setprio(1);
    MFMA16(4, 2, 4);
    __builtin_amdgcn_s_setprio(0);
    __builtin_amdgcn_s_barrier();
    __builtin_amdgcn_s_setprio(1);
    MFMA16(4, 0, 0);
    __builtin_amdgcn_s_setprio(0);
    asm volatile("s_waitcnt vmcnt(0)");
    __builtin_amdgcn_s_barrier();
  }

#pragma unroll
  for (int ii = 0; ii < 8; ++ii) {
#pragma unroll
    for (int q = 0; q < 4; ++q) {
      float mx = fmaxf(fmaxf(acc[ii][0][q], acc[ii][1][q]),
                       fmaxf(acc[ii][2][q], acc[ii][3][q]));
      mx = fmaxf(mx, __shfl_xor(mx, 1, 64));
      mx = fmaxf(mx, __shfl_xor(mx, 2, 64));
      mx = fmaxf(mx, __shfl_xor(mx, 4, 64));
      mx = fmaxf(mx, __shfl_xor(mx, 8, 64));
      float sm = 0.f;
#pragma unroll
      for (int jj = 0; jj < 4; ++jj) sm += __expf(acc[ii][jj][q] - mx);
      sm += __shfl_xor(sm, 1, 64);
      sm += __shfl_xor(sm, 2, 64);
      sm += __shfl_xor(sm, 4, 64);
      sm += __shfl_xor(sm, 8, 64);
      int lrow = wm * 128 + ii * 16 + g * 4 + q;
      if (frow == 0) { pml[lrow][wn] = mx; psl[lrow][wn] = sm; }
      size_t off = (size_t)(bm * 256 + lrow) * V + gc0 + bn * 256 + wn * 64 + frow;
#pragma unroll
      for (int jj = 0; jj < 4; ++jj) C[off + jj * 16] = acc[ii][jj][q];
    }
  }
  __syncthreads();
  if (tid < 256) {
    float m = fmaxf(fmaxf(pml[tid][0], pml[tid][1]), fmaxf(pml[tid][2], pml[tid][3]));
    float s = 0.f;
#pragma unroll
    for (int w4 = 0; w4 < 4; ++w4) s += psl[tid][w4] * __expf(pml[tid][w4] - m);
    size_t grow = bm * 256 + tid;
    int pb = gc0 / 256 + bn;
    pm[grow * PBT + pb] = m;
    ps[grow * PBT + pb] = s;
  }
#undef STAGE
#undef LDA
#undef LDB
#undef MFMA16
}

// ---- MFMA flash attention, balanced + 8-wave parallel pair ----
__global__ __launch_bounds__(512) void k_fattn(const u16* __restrict__ qkv,
                                               u16* __restrict__ y) {
  __shared__ __attribute__((aligned(16))) u16 lQ[2][64 * 64];
  __shared__ __attribute__((aligned(16))) u16 lK[64 * 64];
  __shared__ __attribute__((aligned(16))) u16 lVt[64 * 64];
  __shared__ __attribute__((aligned(16))) u16 lP[128 * 64];
  int tid = threadIdx.x;
  int w = tid >> 6, lane = tid & 63;
  int tq = w >> 2, ws4 = w & 3;
  int xi = blockIdx.x;
  int bh = blockIdx.y, b = bh / H, h = bh - b * H;
  int myqt = tq ? xi : (15 - xi);
  const u16* base = qkv + (size_t)b * T * D3 + h * DH;
  int srow = lane >> 3;
  int scu = lane & 7;
  int frow = lane & 15, g = lane >> 4;
  int s16 = ws4 * 16;
  int qrow = g * 4;
  int f7 = frow & 7;

#pragma unroll
  for (int c = 0; c < 2; ++c) {
    int row = s16 + c * 8 + srow;
    int gcu = scu ^ (row & 7);
    gll16(base + (size_t)(myqt * 64 + row) * D3 + gcu * 8,
          &lQ[tq][(s16 + c * 8) * 64]);
  }

  float m_r[4], l_r[4];
  f32x4 o[4];
#pragma unroll
  for (int i = 0; i < 4; ++i) { m_r[i] = -1e30f; l_r[i] = 0.f; o[i] = (f32x4)(0.f); }

  int ktmax = 15 - xi;
  int kvrow = w * 8 + srow;
  uint4 kr = *(const uint4*)(base + D + (size_t)kvrow * D3 + scu * 8);
  uint4 vr = *(const uint4*)(base + 2 * D + (size_t)kvrow * D3 + scu * 8);

  for (int kt = 0; kt <= ktmax; ++kt) {
    __syncthreads();
    int k0 = kt * 64;
    *(uint4*)(lK + kvrow * 64 + (scu ^ (kvrow & 7)) * 8) = kr;
    {
      unsigned vals[4] = {vr.x, vr.y, vr.z, vr.w};
#pragma unroll
      for (int e = 0; e < 4; ++e) {
        lVt[swzi(scu * 8 + 2 * e, kvrow)]     = (u16)(vals[e] & 0xffff);
        lVt[swzi(scu * 8 + 2 * e + 1, kvrow)] = (u16)(vals[e] >> 16);
      }
    }
    __syncthreads();
    if (kt < ktmax) {
      int rown = k0 + 64 + kvrow;
      kr = *(const uint4*)(base + D + (size_t)rown * D3 + scu * 8);
      vr = *(const uint4*)(base + 2 * D + (size_t)rown * D3 + scu * 8);
    }

    if (tq == 0 || kt <= xi) {
      bool diag = (kt == myqt);
      const u16* lq = &lQ[tq][0];
      bf16x8 aq0 = *(const bf16x8*)(lq + (s16 + frow) * 64 + (g ^ f7) * 8);
      bf16x8 aq1 = *(const bf16x8*)(lq + (s16 + frow) * 64 + ((g + 4) ^ f7) * 8);
      f32x4 sv[4];
#pragma unroll
      for (int kn = 0; kn < 4; ++kn) {
        bf16x8 bk0 = *(const bf16x8*)(lK + (kn * 16 + frow) * 64 + (g ^ f7) * 8);
        bf16x8 bk1 = *(const bf16x8*)(lK + (kn * 16 + frow) * 64 + ((g + 4) ^ f7) * 8);
        sv[kn] = __builtin_amdgcn_mfma_f32_16x16x32_bf16(aq0, bk0, (f32x4)(0.f), 0, 0, 0);
        sv[kn] = __builtin_amdgcn_mfma_f32_16x16x32_bf16(aq1, bk1, sv[kn], 0, 0, 0);
      }
#pragma unroll
      for (int kn = 0; kn < 4; ++kn)
#pragma unroll
        for (int qi = 0; qi < 4; ++qi) {
          float v = sv[kn][qi] * SCALE;
          if (diag) {
            int qg = myqt * 64 + s16 + qrow + qi;
            int kg = k0 + kn * 16 + frow;
            if (kg > qg) v = -1e30f;
          }
          sv[kn][qi] = v;
        }
#pragma unroll
      for (int qi = 0; qi < 4; ++qi) {
        float rm = fmaxf(fmaxf(sv[0][qi], sv[1][qi]), fmaxf(sv[2][qi], sv[3][qi]));
        rm = fmaxf(rm, __shfl_xor(rm, 1, 64));
        rm = fmaxf(rm, __shfl_xor(rm, 2, 64));
        rm = fmaxf(rm, __shfl_xor(rm, 4, 64));
        rm = fmaxf(rm, __shfl_xor(rm, 8, 64));
        float mn = fmaxf(m_r[qi], rm);
        float alpha = __expf(m_r[qi] - mn);
        m_r[qi] = mn;
        float rs = 0.f;
#pragma unroll
        for (int kn = 0; kn < 4; ++kn) {
          float p = __expf(sv[kn][qi] - mn);
          sv[kn][qi] = p;
          rs += p;
        }
        rs += __shfl_xor(rs, 1, 64);
        rs += __shfl_xor(rs, 2, 64);
        rs += __shfl_xor(rs, 4, 64);
        rs += __shfl_xor(rs, 8, 64);
        l_r[qi] = l_r[qi] * alpha + rs;
#pragma unroll
        for (int df = 0; df < 4; ++df) o[df][qi] *= alpha;
      }
#pragma unroll
      for (int kn = 0; kn < 4; ++kn)
#pragma unroll
        for (int qi = 0; qi < 4; ++qi)
          lP[swzi(w * 16 + qrow + qi, kn * 16 + frow)] = f2b(sv[kn][qi]);
      bf16x8 pa0 = *(const bf16x8*)(lP + swzi(w * 16 + frow, g * 8));
      bf16x8 pa1 = *(const bf16x8*)(lP + swzi(w * 16 + frow, 32 + g * 8));
#pragma unroll
      for (int df = 0; df < 4; ++df) {
        bf16x8 bv0 = *(const bf16x8*)(lVt + swzi(df * 16 + frow, g * 8));
        bf16x8 bv1 = *(const bf16x8*)(lVt + swzi(df * 16 + frow, 32 + g * 8));
        o[df] = __builtin_amdgcn_mfma_f32_16x16x32_bf16(pa0, bv0, o[df], 0, 0, 0);
        o[df] = __builtin_amdgcn_mfma_f32_16x16x32_bf16(pa1, bv1, o[df], 0, 0, 0);
      }
    }
  }

#pragma unroll
  for (int df = 0; df < 4; ++df)
#pragma unroll
    for (int qi = 0; qi < 4; ++qi) {
      int qg = myqt * 64 + s16 + qrow + qi;
      y[(size_t)(b * T + qg) * D + h * DH + df * 16 + frow] =
          f2b(o[df][qi] / l_r[qi]);
    }
}

// ---- final LSE + NLL from partials; one wave per row ----
__global__ __launch_bounds__(256) void k_loss_rows(
    const float* __restrict__ pm, const float* __restrict__ ps,
    const float* __restrict__ logits, const int* __restrict__ targets,
    float* __restrict__ nll) {
  int lane = threadIdx.x & 63, wid = threadIdx.x >> 6;
  int row = blockIdx.x * 4 + wid;
  const float* pmr = pm + (size_t)row * PBT;
  const float* psr = ps + (size_t)row * PBT;
  float m = -1e30f;
  for (int i = lane; i < PBT; i += 64) m = fmaxf(m, pmr[i]);
#pragma unroll
  for (int off = 32; off; off >>= 1) m = fmaxf(m, __shfl_xor(m, off, 64));
  float s = 0.f;
  for (int i = lane; i < PBT; i += 64) s += psr[i] * __expf(pmr[i] - m);
#pragma unroll
  for (int off = 32; off; off >>= 1) s += __shfl_xor(s, off, 64);
  if (lane == 0) {
    int tgt = targets[row];
    nll[row] = (tgt != -100) ? (m + logf(s) - logits[(size_t)row * V + tgt]) : 0.f;
  }
}

__global__ __launch_bounds__(256) void k_loss_final(const float* __restrict__ nll,
                                                    const int* __restrict__ targets,
                                                    float* __restrict__ out) {
  __shared__ float buf4[4];
  float s = 0.f, c = 0.f;
  for (int i = threadIdx.x; i < M; i += 256) {
    s += nll[i];
    c += (targets[i] != -100) ? 1.f : 0.f;
  }
  s = block_reduce(s, false, buf4);
  c = block_reduce(c, false, buf4);
  if (threadIdx.x == 0) out[0] = s / fmaxf(c, 1.f);
}

extern "C" void kernel_launch(void* const* d_in, const int* in_sizes, int n_in,
                              void* d_out, int out_size, void* d_ws, size_t ws_size,
                              hipStream_t stream) {
  const int* idx       = (const int*)d_in[0];
  const int* targets   = (const int*)d_in[1];
  const float* tok     = (const float*)d_in[2];
  const float* pos     = (const float*)d_in[3];
  const float* qkv_w   = (const float*)d_in[4];
  const float* qkv_b   = (const float*)d_in[5];
  const float* proj_w  = (const float*)d_in[6];
  const float* proj_b  = (const float*)d_in[7];
  const float* fc1_w   = (const float*)d_in[8];
  const float* fc1_b   = (const float*)d_in[9];
  const float* fc2_w   = (const float*)d_in[10];
  const float* fc2_b   = (const float*)d_in[11];
  const float* ln1_w   = (const float*)d_in[12];
  const float* ln1_b   = (const float*)d_in[13];
  const float* ln2_w   = (const float*)d_in[14];
  const float* ln2_b   = (const float*)d_in[15];
  const float* lnf_w   = (const float*)d_in[16];
  const float* lnf_b   = (const float*)d_in[17];

  float* logits = (float*)d_out;

  // ---- ws layout ----
  char* ws = (char*)d_ws;
  float* x   = (float*)ws;                  // M*D f32        12.58 MB
  u16* hb    = (u16*)(ws + 12582912);       // M*D bf16        6.29 MB
  u16* yb    = (u16*)(ws + 18874368);       // M*D bf16        6.29 MB
  u16* wb    = (u16*)(ws + 25165824);       // lm_head B bf16 (chunk or full tok)
  bool big = ws_size >= (size_t)(25165824 + 49152000 + 2048000 * 2 + 16384);
  float* pm, * ps, * nll;
  if (big) {
    pm  = (float*)(ws + 25165824 + 49152000);
    ps  = (float*)(ws + 25165824 + 49152000 + 2048000);
    nll = (float*)(ws + 25165824 + 49152000 + 4096000);
  } else {
    pm  = (float*)(ws + 34996224);
    ps  = (float*)(ws + 37044224);
    nll = (float*)(ws + 39092224);
  }

  // ---- d_out scratch (dead before logits are written) ----
  u16* qkvb   = (u16*)logits;                        // M*D3 bf16
  u16* f1b    = (u16*)(logits + 9437184);            // M*F bf16
  u16* wqkv   = (u16*)(logits + 15728640);           // contiguous weights (ends ~176MB)
  u16* wproj  = (u16*)(logits + 22806528);
  u16* wfc1   = (u16*)(logits + 25165824);
  u16* wfc2   = (u16*)(logits + 34603008);
  float* fc2p = (float*)((char*)logits + 201326592); // 4x M*D f32 split-K partials

  {
    const int NW4 = (L * D3 * D + L * D * D + L * F * D + L * D * F) / 4;
    k_cvtw<<<(NW4 + 255) / 256, 256, 0, stream>>>(qkv_w, proj_w, fc1_w, fc2_w, wqkv);
  }

  k_embed<<<(M * D) / 256, 256, 0, stream>>>(idx, tok, pos, x);

  for (int l = 0; l < L; ++l) {
    if (l == 0)
      k_lnorm<<<M / 4, 256, 0, stream>>>(x, ln1_w, ln1_b, hb);
    else
      k_lncomb<<<M / 4, 256, 0, stream>>>(x, fc2p, fc2_b + (size_t)(l - 1) * D,
                                          ln1_w + (size_t)l * D, ln1_b + (size_t)l * D, hb);
    k_gemm8<<<dim3(D3 / 128, M / 128), 512, 0, stream>>>(
        hb, wqkv + (size_t)l * D3 * D, qkv_b + (size_t)l * D3, nullptr, qkvb, D, D, D3, 9);
    k_fattn<<<dim3(8, BATCH * H), 512, 0, stream>>>(qkvb, yb);
    k_gemm8<<<dim3(D / 128, M / 128), 512, 0, stream>>>(
        yb, wproj + (size_t)l * D * D, proj_b + (size_t)l * D, x, x, D, D, D, 3);
    k_lnorm<<<M / 4, 256, 0, stream>>>(x, ln2_w + (size_t)l * D, ln2_b + (size_t)l * D, hb);
    k_gemm8<<<dim3(F / 128, M / 128), 512, 0, stream>>>(
        hb, wfc1 + (size_t)l * F * D, fc1_b + (size_t)l * F, nullptr, f1b, D, D, F, 13);
    // fc2 split-K=4: partials only; combine fused into next LN
    k_gemm8<<<dim3(D / 128, M / 128, 4), 512, 0, stream>>>(
        f1b, wfc2 + (size_t)l * D * F, nullptr, nullptr, fc2p, 768, F, D, 16);
  }

  k_lncomb<<<M / 4, 256, 0, stream>>>(x, fc2p, fc2_b + (size_t)(L - 1) * D,
                                      lnf_w, lnf_b, hb);
  if (big) {
    k_cvt<<<(V * D / 4 + 255) / 256, 256, 0, stream>>>(tok, wb, V * D / 4);
    k_lm256<<<dim3(V / 256, M / 256), 512, 0, stream>>>(
        hb, wb, logits, pm, ps, 0);
  } else {
    for (int c = 0; c < 5; ++c) {
      k_cvt<<<(VCHUNK * D / 4 + 255) / 256, 256, 0, stream>>>(
          tok + (size_t)c * VCHUNK * D, wb, VCHUNK * D / 4);
      k_lm256<<<dim3(VCHUNK / 256, M / 256), 512, 0, stream>>>(
          hb, wb, logits, pm, ps, c * VCHUNK);
    }
  }
  k_loss_rows<<<M / 4, 256, 0, stream>>>(pm, ps, logits, targets, nll);
  k_loss_final<<<1, 256, 0, stream>>>(nll, targets, logits + (size_t)M * V);
}

// Round 17
// 1873.295 us; speedup vs baseline: 1.0202x; 1.0134x over previous
//
#include <hip/hip_runtime.h>
#include <hip/hip_bf16.h>
#include <math.h>

#define BATCH 4
#define T 1024
#define D 768
#define L 8
#define H 12
#define F 3072
#define V 32000
#define DH 64
#define M (BATCH*T)   // 4096
#define D3 (3*D)      // 2304
#define SCALE 0.125f
#define VCHUNK 6400   // lm_head N-chunk — fallback path
#define PBT 125       // col-partial blocks (32000/256)

typedef unsigned short u16;
typedef __attribute__((ext_vector_type(8))) short bf16x8;
typedef __attribute__((ext_vector_type(4))) float f32x4;

__device__ inline u16 f2b(float f) {
  __hip_bfloat16 h = __float2bfloat16(f);
  return *(u16*)&h;
}

// async global->LDS, 16B per lane; LDS dest is wave-uniform base + lane*16
__device__ inline void gll16(const void* g, void* l) {
  __builtin_amdgcn_global_load_lds(
      (const __attribute__((address_space(1))) unsigned int*)g,
      (__attribute__((address_space(3))) unsigned int*)l, 16, 0, 0);
}

// XOR swizzle for [*][64] u16 LDS tiles (manual-write paths)
__device__ inline int swzi(int r, int c) {
  return (r * 64 + c) ^ ((((r & 7) ^ ((r >> 3) & 7))) << 3);
}

// ---- block-wide reduce (exactly 256 threads / 4 waves) ----
__device__ inline float block_reduce(float v, bool is_max, float* buf4) {
  int lane = threadIdx.x & 63, wid = threadIdx.x >> 6;
#pragma unroll
  for (int off = 32; off; off >>= 1) {
    float o = __shfl_down(v, off, 64);
    v = is_max ? fmaxf(v, o) : v + o;
  }
  if (lane == 0) buf4[wid] = v;
  __syncthreads();
  float r = is_max ? fmaxf(fmaxf(buf4[0], buf4[1]), fmaxf(buf4[2], buf4[3]))
                   : buf4[0] + buf4[1] + buf4[2] + buf4[3];
  __syncthreads();
  return r;
}

// ---- x = tok_emb[idx] + pos_emb ----
__global__ __launch_bounds__(256) void k_embed(const int* __restrict__ idx,
                                               const float* __restrict__ tok,
                                               const float* __restrict__ pos,
                                               float* __restrict__ x) {
  int i = blockIdx.x * 256 + threadIdx.x;
  int row = i / D, d = i - row * D;
  int t = row & (T - 1);
  x[i] = tok[(size_t)idx[row] * D + d] + pos[(size_t)t * D + d];
}

// ---- f32 -> bf16 convert, 4 elems/thread ----
__global__ __launch_bounds__(256) void k_cvt(const float* __restrict__ in,
                                             u16* __restrict__ out, int n4) {
  int i = blockIdx.x * 256 + threadIdx.x;
  if (i >= n4) return;
  float4 v = ((const float4*)in)[i];
  ushort4 o;
  o.x = f2b(v.x); o.y = f2b(v.y); o.z = f2b(v.z); o.w = f2b(v.w);
  ((ushort4*)out)[i] = o;
}

// ---- all block weights f32 -> bf16 in one launch (contiguous dest) ----
__global__ __launch_bounds__(256) void k_cvtw(const float* __restrict__ q,
                                              const float* __restrict__ p,
                                              const float* __restrict__ f1,
                                              const float* __restrict__ f2,
                                              u16* __restrict__ out) {
  const int N0 = L * D3 * D / 4, N1 = L * D * D / 4;
  const int N2 = L * F * D / 4, N3 = L * D * F / 4;
  int i = blockIdx.x * 256 + threadIdx.x;
  if (i >= N0 + N1 + N2 + N3) return;
  const float* src;
  int j = i;
  if (i < N0) { src = q; }
  else if (i < N0 + N1) { src = p; j = i - N0; }
  else if (i < N0 + N1 + N2) { src = f1; j = i - N0 - N1; }
  else { src = f2; j = i - N0 - N1 - N2; }
  float4 v = ((const float4*)src)[j];
  ushort4 o;
  o.x = f2b(v.x); o.y = f2b(v.y); o.z = f2b(v.z); o.w = f2b(v.w);
  ((ushort4*)out)[i] = o;
}

// ---- LayerNorm: one WAVE per row of 768, bf16 out; no LDS, no barriers ----
__global__ __launch_bounds__(256) void k_lnorm(const float* __restrict__ x,
                                               const float* __restrict__ w,
                                               const float* __restrict__ b,
                                               u16* __restrict__ out) {
  int lane = threadIdx.x & 63, wid = threadIdx.x >> 6;
  int row = blockIdx.x * 4 + wid;
  const float4* xr = (const float4*)(x + (size_t)row * D);
  float4 v[3];
  float s = 0.f, ss = 0.f;
#pragma unroll
  for (int p = 0; p < 3; ++p) {
    v[p] = xr[lane + 64 * p];
    s += v[p].x + v[p].y + v[p].z + v[p].w;
    ss += v[p].x * v[p].x + v[p].y * v[p].y + v[p].z * v[p].z + v[p].w * v[p].w;
  }
#pragma unroll
  for (int off = 32; off; off >>= 1) {
    s += __shfl_xor(s, off, 64);
    ss += __shfl_xor(ss, off, 64);
  }
  float mu = s * (1.0f / D);
  float var = ss * (1.0f / D) - mu * mu;
  float rs = rsqrtf(var + 1e-5f);
  ushort4* orow = (ushort4*)(out + (size_t)row * D);
#pragma unroll
  for (int p = 0; p < 3; ++p) {
    float4 wv = ((const float4*)w)[lane + 64 * p];
    float4 bv = ((const float4*)b)[lane + 64 * p];
    ushort4 o;
    o.x = f2b((v[p].x - mu) * rs * wv.x + bv.x);
    o.y = f2b((v[p].y - mu) * rs * wv.y + bv.y);
    o.z = f2b((v[p].z - mu) * rs * wv.z + bv.z);
    o.w = f2b((v[p].w - mu) * rs * wv.w + bv.w);
    orow[lane + 64 * p] = o;
  }
}

// ---- fused: x += sum(nparts split-K partials) + bias2; out = LN(x); x updated ----
__global__ __launch_bounds__(256) void k_lncomb(float* __restrict__ x,
                                                const float* __restrict__ parts,
                                                const float* __restrict__ bias2,
                                                const float* __restrict__ w,
                                                const float* __restrict__ b,
                                                u16* __restrict__ out, int nparts) {
  int lane = threadIdx.x & 63, wid = threadIdx.x >> 6;
  int row = blockIdx.x * 4 + wid;
  float4* xr = (float4*)(x + (size_t)row * D);
  float4 v[3];
  float s = 0.f, ss = 0.f;
#pragma unroll
  for (int p = 0; p < 3; ++p) {
    v[p] = xr[lane + 64 * p];
    for (int pp = 0; pp < nparts; ++pp) {
      float4 pv = ((const float4*)(parts + (size_t)pp * M * D + (size_t)row * D))[lane + 64 * p];
      v[p].x += pv.x; v[p].y += pv.y; v[p].z += pv.z; v[p].w += pv.w;
    }
    float4 b2 = ((const float4*)bias2)[lane + 64 * p];
    v[p].x += b2.x; v[p].y += b2.y; v[p].z += b2.z; v[p].w += b2.w;
    s += v[p].x + v[p].y + v[p].z + v[p].w;
    ss += v[p].x * v[p].x + v[p].y * v[p].y + v[p].z * v[p].z + v[p].w * v[p].w;
  }
#pragma unroll
  for (int off = 32; off; off >>= 1) {
    s += __shfl_xor(s, off, 64);
    ss += __shfl_xor(ss, off, 64);
  }
  float mu = s * (1.0f / D);
  float var = ss * (1.0f / D) - mu * mu;
  float rs = rsqrtf(var + 1e-5f);
  ushort4* orow = (ushort4*)(out + (size_t)row * D);
#pragma unroll
  for (int p = 0; p < 3; ++p) {
    xr[lane + 64 * p] = v[p];
    float4 wv = ((const float4*)w)[lane + 64 * p];
    float4 bv = ((const float4*)b)[lane + 64 * p];
    ushort4 o;
    o.x = f2b((v[p].x - mu) * rs * wv.x + bv.x);
    o.y = f2b((v[p].y - mu) * rs * wv.y + bv.y);
    o.z = f2b((v[p].z - mu) * rs * wv.z + bv.z);
    o.w = f2b((v[p].w - mu) * rs * wv.w + bv.w);
    orow[lane + 64 * p] = o;
  }
}

// ---- layer GEMM: C[M,N] = A[M,K] @ W[N,K]^T, 128x128 tile, 8 waves,
//      BK=64 double-buffered, counted vmcnt(4) pipeline, swizzled LDS ----
// flags: 1=bias, 2=residual add (f32), 4=exact gelu, 8=bf16 output,
//        16=split-K partial (f32 out, no bias/resid; K-range = blockIdx.z)
__global__ __launch_bounds__(512, 2) void k_gemm8(
    const u16* __restrict__ A, const u16* __restrict__ W,
    const float* __restrict__ bias, const float* __restrict__ resid,
    void* __restrict__ Cout, int kLen, int kStride, int ldC, int flags) {
  __shared__ __attribute__((aligned(16))) u16 lds[2][2][128 * 64];
  int tid = threadIdx.x, w = tid >> 6, lane = tid & 63;
  int wm = w >> 2, wn = w & 3;
  int bn = blockIdx.x, bm = blockIdx.y;
  int frow = lane & 15, g = lane >> 4;
  int sr = lane >> 3, scu = lane & 7;
  int kz = (flags & 16) ? blockIdx.z * kLen : 0;
  const u16* Ab = A + (size_t)bm * 128 * kStride + kz;
  const u16* Wb = W + (size_t)bn * 128 * kStride + kz;
  float* Cp = (float*)Cout + ((flags & 16) ? (size_t)blockIdx.z * M * (size_t)ldC : 0);
  int NT = kLen >> 6;

  f32x4 acc[4][2];
#pragma unroll
  for (int i = 0; i < 4; ++i)
#pragma unroll
    for (int j = 0; j < 2; ++j) acc[i][j] = (f32x4)(0.f);

#define STG(t)                                                            \
  {                                                                       \
    _Pragma("unroll") for (int rr = 0; rr < 2; ++rr) {                    \
      int row = rr * 64 + w * 8 + sr;                                     \
      int gcu = scu ^ (row & 7);                                          \
      gll16(Ab + (size_t)row * kStride + (t) * 64 + gcu * 8,              \
            &lds[(t) & 1][0][(rr * 64 + w * 8) * 64]);                    \
      gll16(Wb + (size_t)row * kStride + (t) * 64 + gcu * 8,              \
            &lds[(t) & 1][1][(rr * 64 + w * 8) * 64]);                    \
    }                                                                     \
  }

  STG(0);
  asm volatile("s_waitcnt vmcnt(0)");
  __builtin_amdgcn_s_barrier();

  for (int t = 0; t < NT; ++t) {
    if (t + 1 < NT) {
      STG(t + 1);                          // next tile into other buffer
      asm volatile("s_waitcnt vmcnt(4)");  // tile t landed; t+1 stays in flight
    } else {
      asm volatile("s_waitcnt vmcnt(0)");
    }
    __builtin_amdgcn_s_barrier();
    const u16* bA = &lds[t & 1][0][0];
    const u16* bB = &lds[t & 1][1][0];
    bf16x8 ar[8], br[4];
#pragma unroll
    for (int i = 0; i < 4; ++i)
#pragma unroll
      for (int kk = 0; kk < 2; ++kk) {
        int r = wm * 64 + i * 16 + frow;
        ar[i * 2 + kk] = *(const bf16x8*)(bA + r * 64 + ((g + kk * 4) ^ (r & 7)) * 8);
      }
#pragma unroll
    for (int j = 0; j < 2; ++j)
#pragma unroll
      for (int kk = 0; kk < 2; ++kk) {
        int r = wn * 32 + j * 16 + frow;
        br[j * 2 + kk] = *(const bf16x8*)(bB + r * 64 + ((g + kk * 4) ^ (r & 7)) * 8);
      }
    __builtin_amdgcn_s_setprio(1);
#pragma unroll
    for (int i = 0; i < 4; ++i)
#pragma unroll
      for (int j = 0; j < 2; ++j)
#pragma unroll
        for (int kk = 0; kk < 2; ++kk)
          acc[i][j] = __builtin_amdgcn_mfma_f32_16x16x32_bf16(
              ar[i * 2 + kk], br[j * 2 + kk], acc[i][j], 0, 0, 0);
    __builtin_amdgcn_s_setprio(0);
    __builtin_amdgcn_s_barrier();  // reads of buf[t] done before overwrite
  }
#undef STG

  int m0 = bm * 128 + wm * 64 + g * 4;
  int n0 = bn * 128 + wn * 32 + frow;
#pragma unroll
  for (int i = 0; i < 4; ++i) {
#pragma unroll
    for (int j = 0; j < 2; ++j) {
      int n = n0 + j * 16;
      float bv = (flags & 1) ? bias[n] : 0.f;
#pragma unroll
      for (int q = 0; q < 4; ++q) {
        int m = m0 + i * 16 + q;
        size_t off = (size_t)m * ldC + n;
        float v = acc[i][j][q] + bv;
        if (flags & 4) v = 0.5f * v * (1.0f + erff(v * 0.70710678118f));
        if (flags & 2) v += resid[off];
        if (flags & 8) ((u16*)Cout)[off] = f2b(v);
        else           Cp[off] = v;
      }
    }
  }
}

// ---- lm_head 256x256 GEMM, K=768 fixed, 8 waves, dbuf + 4-phase + fused LSE.
// Round-14 proven schedule (308 us): next-tile stages in phases A/B, single
// vmcnt(0) drain at phase D. FROZEN — 3 restructurings all regressed.
__global__ __launch_bounds__(512, 2) void k_lm256(
    const u16* __restrict__ A, const u16* __restrict__ B,
    float* __restrict__ C, float* __restrict__ pm, float* __restrict__ ps,
    int gc0) {
  __shared__ __attribute__((aligned(16))) u16 lds[2][2][2][128 * 64];
  __shared__ float pml[256][4], psl[256][4];
  const int K = 768, NT = 12;
  int tid = threadIdx.x, w = tid >> 6, lane = tid & 63;
  int wm = w >> 2, wn = w & 3;
  int bm = blockIdx.y, bn = blockIdx.x;
  int frow = lane & 15, g = lane >> 4;
  int sr = lane >> 3, scu = lane & 7;
  const u16* Abase = A + (size_t)bm * 256 * K;
  const u16* Bbase = B + (size_t)bn * 256 * K;

  f32x4 acc[8][4];
#pragma unroll
  for (int i = 0; i < 8; ++i)
#pragma unroll
    for (int j = 0; j < 4; ++j) acc[i][j] = (f32x4)(0.f);

#define STAGE(t, h)                                                       \
  {                                                                       \
    const u16* src = ((h) < 2 ? Abase : Bbase) + (size_t)(((h)&1) * 128) * K; \
    u16* dst = &lds[(t) & 1][(h) >> 1][(h)&1][0];                         \
    _Pragma("unroll") for (int rr = 0; rr < 2; ++rr) {                    \
      int row = rr * 64 + w * 8 + sr;                                     \
      int gcu = scu ^ (row & 7);                                          \
      gll16(src + (size_t)row * K + (t) * 64 + gcu * 8,                   \
            dst + (rr * 64 + w * 8) * 64);                                \
    }                                                                     \
  }

  bf16x8 ar[8], br[8];
#define LDA(T_, ILO)                                                      \
  {                                                                       \
    const u16* base = &lds[(T_)&1][0][wm][0];                             \
    _Pragma("unroll") for (int ii = 0; ii < 4; ++ii)                      \
    _Pragma("unroll") for (int kk = 0; kk < 2; ++kk) {                    \
      int ri = ((ILO) + ii) * 16 + frow;                                  \
      int u = (g + kk * 4) ^ (ri & 7);                                    \
      ar[ii * 2 + kk] = *(const bf16x8*)(base + ri * 64 + u * 8);         \
    }                                                                     \
  }
#define LDB(T_, JLO, BO)                                                  \
  {                                                                       \
    const u16* base = &lds[(T_)&1][1][wn >> 1][0];                        \
    _Pragma("unroll") for (int jj = 0; jj < 2; ++jj)                      \
    _Pragma("unroll") for (int kk = 0; kk < 2; ++kk) {                    \
      int rj = (wn & 1) * 64 + ((JLO) + jj) * 16 + frow;                  \
      int u = (g + kk * 4) ^ (rj & 7);                                    \
      br[(BO) + jj * 2 + kk] = *(const bf16x8*)(base + rj * 64 + u * 8);  \
    }                                                                     \
  }
#define MFMA16(ILO, JLO, BO)                                              \
  _Pragma("unroll") for (int ii = 0; ii < 4; ++ii)                        \
  _Pragma("unroll") for (int jj = 0; jj < 2; ++jj)                        \
  _Pragma("unroll") for (int kk = 0; kk < 2; ++kk)                        \
    acc[(ILO) + ii][(JLO) + jj] = __builtin_amdgcn_mfma_f32_16x16x32_bf16( \
        ar[ii * 2 + kk], br[(BO) + jj * 2 + kk], acc[(ILO) + ii][(JLO) + jj], 0, 0, 0);

  STAGE(0, 0); STAGE(0, 1); STAGE(0, 2); STAGE(0, 3);
  asm volatile("s_waitcnt vmcnt(0)");
  __builtin_amdgcn_s_barrier();

  for (int t = 0; t < NT; ++t) {
    bool pf = (t + 1 < NT);
    LDA(t, 0); LDB(t, 0, 0);
    if (pf) { STAGE(t + 1, 0); STAGE(t + 1, 1); }
    __builtin_amdgcn_s_setprio(1);
    MFMA16(0, 0, 0);
    __builtin_amdgcn_s_setprio(0);
    __builtin_amdgcn_s_barrier();
    LDB(t, 2, 4);
    if (pf) { STAGE(t + 1, 2); STAGE(t + 1, 3); }
    __builtin_amdgcn_s_setprio(1);
    MFMA16(0, 2, 4);
    __builtin_amdgcn_s_setprio(0);
    __builtin_amdgcn_s_barrier();
    LDA(t, 4);
    __builtin_amdgcn_s_setprio(1);
    MFMA16(4, 2, 4);
    __builtin_amdgcn_s_setprio(0);
    __builtin_amdgcn_s_barrier();
    __builtin_amdgcn_s_setprio(1);
    MFMA16(4, 0, 0);
    __builtin_amdgcn_s_setprio(0);
    asm volatile("s_waitcnt vmcnt(0)");
    __builtin_amdgcn_s_barrier();
  }

#pragma unroll
  for (int ii = 0; ii < 8; ++ii) {
#pragma unroll
    for (int q = 0; q < 4; ++q) {
      float mx = fmaxf(fmaxf(acc[ii][0][q], acc[ii][1][q]),
                       fmaxf(acc[ii][2][q], acc[ii][3][q]));
      mx = fmaxf(mx, __shfl_xor(mx, 1, 64));
      mx = fmaxf(mx, __shfl_xor(mx, 2, 64));
      mx = fmaxf(mx, __shfl_xor(mx, 4, 64));
      mx = fmaxf(mx, __shfl_xor(mx, 8, 64));
      float sm = 0.f;
#pragma unroll
      for (int jj = 0; jj < 4; ++jj) sm += __expf(acc[ii][jj][q] - mx);
      sm += __shfl_xor(sm, 1, 64);
      sm += __shfl_xor(sm, 2, 64);
      sm += __shfl_xor(sm, 4, 64);
      sm += __shfl_xor(sm, 8, 64);
      int lrow = wm * 128 + ii * 16 + g * 4 + q;
      if (frow == 0) { pml[lrow][wn] = mx; psl[lrow][wn] = sm; }
      size_t off = (size_t)(bm * 256 + lrow) * V + gc0 + bn * 256 + wn * 64 + frow;
#pragma unroll
      for (int jj = 0; jj < 4; ++jj) C[off + jj * 16] = acc[ii][jj][q];
    }
  }
  __syncthreads();
  if (tid < 256) {
    float m = fmaxf(fmaxf(pml[tid][0], pml[tid][1]), fmaxf(pml[tid][2], pml[tid][3]));
    float s = 0.f;
#pragma unroll
    for (int w4 = 0; w4 < 4; ++w4) s += psl[tid][w4] * __expf(pml[tid][w4] - m);
    size_t grow = bm * 256 + tid;
    int pb = gc0 / 256 + bn;
    pm[grow * PBT + pb] = m;
    ps[grow * PBT + pb] = s;
  }
#undef STAGE
#undef LDA
#undef LDB
#undef MFMA16
}

// ---- MFMA flash attention, balanced + 8-wave parallel pair ----
__global__ __launch_bounds__(512) void k_fattn(const u16* __restrict__ qkv,
                                               u16* __restrict__ y) {
  __shared__ __attribute__((aligned(16))) u16 lQ[2][64 * 64];
  __shared__ __attribute__((aligned(16))) u16 lK[64 * 64];
  __shared__ __attribute__((aligned(16))) u16 lVt[64 * 64];
  __shared__ __attribute__((aligned(16))) u16 lP[128 * 64];
  int tid = threadIdx.x;
  int w = tid >> 6, lane = tid & 63;
  int tq = w >> 2, ws4 = w & 3;
  int xi = blockIdx.x;
  int bh = blockIdx.y, b = bh / H, h = bh - b * H;
  int myqt = tq ? xi : (15 - xi);
  const u16* base = qkv + (size_t)b * T * D3 + h * DH;
  int srow = lane >> 3;
  int scu = lane & 7;
  int frow = lane & 15, g = lane >> 4;
  int s16 = ws4 * 16;
  int qrow = g * 4;
  int f7 = frow & 7;

#pragma unroll
  for (int c = 0; c < 2; ++c) {
    int row = s16 + c * 8 + srow;
    int gcu = scu ^ (row & 7);
    gll16(base + (size_t)(myqt * 64 + row) * D3 + gcu * 8,
          &lQ[tq][(s16 + c * 8) * 64]);
  }

  float m_r[4], l_r[4];
  f32x4 o[4];
#pragma unroll
  for (int i = 0; i < 4; ++i) { m_r[i] = -1e30f; l_r[i] = 0.f; o[i] = (f32x4)(0.f); }

  int ktmax = 15 - xi;
  int kvrow = w * 8 + srow;
  uint4 kr = *(const uint4*)(base + D + (size_t)kvrow * D3 + scu * 8);
  uint4 vr = *(const uint4*)(base + 2 * D + (size_t)kvrow * D3 + scu * 8);

  for (int kt = 0; kt <= ktmax; ++kt) {
    __syncthreads();
    int k0 = kt * 64;
    *(uint4*)(lK + kvrow * 64 + (scu ^ (kvrow & 7)) * 8) = kr;
    {
      unsigned vals[4] = {vr.x, vr.y, vr.z, vr.w};
#pragma unroll
      for (int e = 0; e < 4; ++e) {
        lVt[swzi(scu * 8 + 2 * e, kvrow)]     = (u16)(vals[e] & 0xffff);
        lVt[swzi(scu * 8 + 2 * e + 1, kvrow)] = (u16)(vals[e] >> 16);
      }
    }
    __syncthreads();
    if (kt < ktmax) {
      int rown = k0 + 64 + kvrow;
      kr = *(const uint4*)(base + D + (size_t)rown * D3 + scu * 8);
      vr = *(const uint4*)(base + 2 * D + (size_t)rown * D3 + scu * 8);
    }

    if (tq == 0 || kt <= xi) {
      bool diag = (kt == myqt);
      const u16* lq = &lQ[tq][0];
      bf16x8 aq0 = *(const bf16x8*)(lq + (s16 + frow) * 64 + (g ^ f7) * 8);
      bf16x8 aq1 = *(const bf16x8*)(lq + (s16 + frow) * 64 + ((g + 4) ^ f7) * 8);
      f32x4 sv[4];
#pragma unroll
      for (int kn = 0; kn < 4; ++kn) {
        bf16x8 bk0 = *(const bf16x8*)(lK + (kn * 16 + frow) * 64 + (g ^ f7) * 8);
        bf16x8 bk1 = *(const bf16x8*)(lK + (kn * 16 + frow) * 64 + ((g + 4) ^ f7) * 8);
        sv[kn] = __builtin_amdgcn_mfma_f32_16x16x32_bf16(aq0, bk0, (f32x4)(0.f), 0, 0, 0);
        sv[kn] = __builtin_amdgcn_mfma_f32_16x16x32_bf16(aq1, bk1, sv[kn], 0, 0, 0);
      }
#pragma unroll
      for (int kn = 0; kn < 4; ++kn)
#pragma unroll
        for (int qi = 0; qi < 4; ++qi) {
          float v = sv[kn][qi] * SCALE;
          if (diag) {
            int qg = myqt * 64 + s16 + qrow + qi;
            int kg = k0 + kn * 16 + frow;
            if (kg > qg) v = -1e30f;
          }
          sv[kn][qi] = v;
        }
#pragma unroll
      for (int qi = 0; qi < 4; ++qi) {
        float rm = fmaxf(fmaxf(sv[0][qi], sv[1][qi]), fmaxf(sv[2][qi], sv[3][qi]));
        rm = fmaxf(rm, __shfl_xor(rm, 1, 64));
        rm = fmaxf(rm, __shfl_xor(rm, 2, 64));
        rm = fmaxf(rm, __shfl_xor(rm, 4, 64));
        rm = fmaxf(rm, __shfl_xor(rm, 8, 64));
        float mn = fmaxf(m_r[qi], rm);
        float alpha = __expf(m_r[qi] - mn);
        m_r[qi] = mn;
        float rs = 0.f;
#pragma unroll
        for (int kn = 0; kn < 4; ++kn) {
          float p = __expf(sv[kn][qi] - mn);
          sv[kn][qi] = p;
          rs += p;
        }
        rs += __shfl_xor(rs, 1, 64);
        rs += __shfl_xor(rs, 2, 64);
        rs += __shfl_xor(rs, 4, 64);
        rs += __shfl_xor(rs, 8, 64);
        l_r[qi] = l_r[qi] * alpha + rs;
#pragma unroll
        for (int df = 0; df < 4; ++df) o[df][qi] *= alpha;
      }
#pragma unroll
      for (int kn = 0; kn < 4; ++kn)
#pragma unroll
        for (int qi = 0; qi < 4; ++qi)
          lP[swzi(w * 16 + qrow + qi, kn * 16 + frow)] = f2b(sv[kn][qi]);
      bf16x8 pa0 = *(const bf16x8*)(lP + swzi(w * 16 + frow, g * 8));
      bf16x8 pa1 = *(const bf16x8*)(lP + swzi(w * 16 + frow, 32 + g * 8));
#pragma unroll
      for (int df = 0; df < 4; ++df) {
        bf16x8 bv0 = *(const bf16x8*)(lVt + swzi(df * 16 + frow, g * 8));
        bf16x8 bv1 = *(const bf16x8*)(lVt + swzi(df * 16 + frow, 32 + g * 8));
        o[df] = __builtin_amdgcn_mfma_f32_16x16x32_bf16(pa0, bv0, o[df], 0, 0, 0);
        o[df] = __builtin_amdgcn_mfma_f32_16x16x32_bf16(pa1, bv1, o[df], 0, 0, 0);
      }
    }
  }

#pragma unroll
  for (int df = 0; df < 4; ++df)
#pragma unroll
    for (int qi = 0; qi < 4; ++qi) {
      int qg = myqt * 64 + s16 + qrow + qi;
      y[(size_t)(b * T + qg) * D + h * DH + df * 16 + frow] =
          f2b(o[df][qi] / l_r[qi]);
    }
}

// ---- final LSE + NLL from partials; one wave per row ----
__global__ __launch_bounds__(256) void k_loss_rows(
    const float* __restrict__ pm, const float* __restrict__ ps,
    const float* __restrict__ logits, const int* __restrict__ targets,
    float* __restrict__ nll) {
  int lane = threadIdx.x & 63, wid = threadIdx.x >> 6;
  int row = blockIdx.x * 4 + wid;
  const float* pmr = pm + (size_t)row * PBT;
  const float* psr = ps + (size_t)row * PBT;
  float m = -1e30f;
  for (int i = lane; i < PBT; i += 64) m = fmaxf(m, pmr[i]);
#pragma unroll
  for (int off = 32; off; off >>= 1) m = fmaxf(m, __shfl_xor(m, off, 64));
  float s = 0.f;
  for (int i = lane; i < PBT; i += 64) s += psr[i] * __expf(pmr[i] - m);
#pragma unroll
  for (int off = 32; off; off >>= 1) s += __shfl_xor(s, off, 64);
  if (lane == 0) {
    int tgt = targets[row];
    nll[row] = (tgt != -100) ? (m + logf(s) - logits[(size_t)row * V + tgt]) : 0.f;
  }
}

__global__ __launch_bounds__(256) void k_loss_final(const float* __restrict__ nll,
                                                    const int* __restrict__ targets,
                                                    float* __restrict__ out) {
  __shared__ float buf4[4];
  float s = 0.f, c = 0.f;
  for (int i = threadIdx.x; i < M; i += 256) {
    s += nll[i];
    c += (targets[i] != -100) ? 1.f : 0.f;
  }
  s = block_reduce(s, false, buf4);
  c = block_reduce(c, false, buf4);
  if (threadIdx.x == 0) out[0] = s / fmaxf(c, 1.f);
}

extern "C" void kernel_launch(void* const* d_in, const int* in_sizes, int n_in,
                              void* d_out, int out_size, void* d_ws, size_t ws_size,
                              hipStream_t stream) {
  const int* idx       = (const int*)d_in[0];
  const int* targets   = (const int*)d_in[1];
  const float* tok     = (const float*)d_in[2];
  const float* pos     = (const float*)d_in[3];
  const float* qkv_w   = (const float*)d_in[4];
  const float* qkv_b   = (const float*)d_in[5];
  const float* proj_w  = (const float*)d_in[6];
  const float* proj_b  = (const float*)d_in[7];
  const float* fc1_w   = (const float*)d_in[8];
  const float* fc1_b   = (const float*)d_in[9];
  const float* fc2_w   = (const float*)d_in[10];
  const float* fc2_b   = (const float*)d_in[11];
  const float* ln1_w   = (const float*)d_in[12];
  const float* ln1_b   = (const float*)d_in[13];
  const float* ln2_w   = (const float*)d_in[14];
  const float* ln2_b   = (const float*)d_in[15];
  const float* lnf_w   = (const float*)d_in[16];
  const float* lnf_b   = (const float*)d_in[17];

  float* logits = (float*)d_out;

  // ---- ws layout ----
  char* ws = (char*)d_ws;
  float* x   = (float*)ws;                  // M*D f32        12.58 MB
  u16* hb    = (u16*)(ws + 12582912);       // M*D bf16        6.29 MB
  u16* yb    = (u16*)(ws + 18874368);       // M*D bf16        6.29 MB
  u16* wb    = (u16*)(ws + 25165824);       // lm_head B bf16 (chunk or full tok)
  bool big = ws_size >= (size_t)(25165824 + 49152000 + 2048000 * 2 + 16384);
  float* pm, * ps, * nll;
  if (big) {
    pm  = (float*)(ws + 25165824 + 49152000);
    ps  = (float*)(ws + 25165824 + 49152000 + 2048000);
    nll = (float*)(ws + 25165824 + 49152000 + 4096000);
  } else {
    pm  = (float*)(ws + 34996224);
    ps  = (float*)(ws + 37044224);
    nll = (float*)(ws + 39092224);
  }

  // ---- d_out scratch (dead before logits are written) ----
  u16* qkvb   = (u16*)logits;                        // M*D3 bf16
  u16* f1b    = (u16*)(logits + 9437184);            // M*F bf16
  u16* wqkv   = (u16*)(logits + 15728640);           // contiguous weights (ends ~176MB)
  u16* wproj  = (u16*)(logits + 22806528);
  u16* wfc1   = (u16*)(logits + 25165824);
  u16* wfc2   = (u16*)(logits + 34603008);
  float* fc2p = (float*)((char*)logits + 201326592); // 4x M*D f32 split-K partials

  {
    const int NW4 = (L * D3 * D + L * D * D + L * F * D + L * D * F) / 4;
    k_cvtw<<<(NW4 + 255) / 256, 256, 0, stream>>>(qkv_w, proj_w, fc1_w, fc2_w, wqkv);
  }

  k_embed<<<(M * D) / 256, 256, 0, stream>>>(idx, tok, pos, x);

  for (int l = 0; l < L; ++l) {
    if (l == 0)
      k_lnorm<<<M / 4, 256, 0, stream>>>(x, ln1_w, ln1_b, hb);
    else
      k_lncomb<<<M / 4, 256, 0, stream>>>(x, fc2p, fc2_b + (size_t)(l - 1) * D,
                                          ln1_w + (size_t)l * D, ln1_b + (size_t)l * D, hb, 4);
    k_gemm8<<<dim3(D3 / 128, M / 128), 512, 0, stream>>>(
        hb, wqkv + (size_t)l * D3 * D, qkv_b + (size_t)l * D3, nullptr, qkvb, D, D, D3, 9);
    k_fattn<<<dim3(8, BATCH * H), 512, 0, stream>>>(qkvb, yb);
    // proj split-K=2: partials only; combine + residual fused into ln2
    k_gemm8<<<dim3(D / 128, M / 128, 2), 512, 0, stream>>>(
        yb, wproj + (size_t)l * D * D, nullptr, nullptr, fc2p, 384, D, D, 16);
    k_lncomb<<<M / 4, 256, 0, stream>>>(x, fc2p, proj_b + (size_t)l * D,
                                        ln2_w + (size_t)l * D, ln2_b + (size_t)l * D, hb, 2);
    k_gemm8<<<dim3(F / 128, M / 128), 512, 0, stream>>>(
        hb, wfc1 + (size_t)l * F * D, fc1_b + (size_t)l * F, nullptr, f1b, D, D, F, 13);
    // fc2 split-K=4: partials only; combine fused into next LN
    k_gemm8<<<dim3(D / 128, M / 128, 4), 512, 0, stream>>>(
        f1b, wfc2 + (size_t)l * D * F, nullptr, nullptr, fc2p, 768, F, D, 16);
  }

  k_lncomb<<<M / 4, 256, 0, stream>>>(x, fc2p, fc2_b + (size_t)(L - 1) * D,
                                      lnf_w, lnf_b, hb, 4);
  if (big) {
    k_cvt<<<(V * D / 4 + 255) / 256, 256, 0, stream>>>(tok, wb, V * D / 4);
    k_lm256<<<dim3(V / 256, M / 256), 512, 0, stream>>>(
        hb, wb, logits, pm, ps, 0);
  } else {
    for (int c = 0; c < 5; ++c) {
      k_cvt<<<(VCHUNK * D / 4 + 255) / 256, 256, 0, stream>>>(
          tok + (size_t)c * VCHUNK * D, wb, VCHUNK * D / 4);
      k_lm256<<<dim3(VCHUNK / 256, M / 256), 512, 0, stream>>>(
          hb, wb, logits, pm, ps, c * VCHUNK);
    }
  }
  k_loss_rows<<<M / 4, 256, 0, stream>>>(pm, ps, logits, targets, nll);
  k_loss_final<<<1, 256, 0, stream>>>(nll, targets, logits + (size_t)M * V);
}

// Round 18
// 1856.294 us; speedup vs baseline: 1.0295x; 1.0092x over previous
//
#include <hip/hip_runtime.h>
#include <hip/hip_bf16.h>
#include <math.h>

#define BATCH 4
#define T 1024
#define D 768
#define L 8
#define H 12
#define F 3072
#define V 32000
#define DH 64
#define M (BATCH*T)   // 4096
#define D3 (3*D)      // 2304
#define SCALE 0.125f
#define VCHUNK 6400   // lm_head N-chunk — fallback path
#define PBT 125       // col-partial blocks (32000/256)

typedef unsigned short u16;
typedef __attribute__((ext_vector_type(8))) short bf16x8;
typedef __attribute__((ext_vector_type(4))) float f32x4;

__device__ inline u16 f2b(float f) {
  __hip_bfloat16 h = __float2bfloat16(f);
  return *(u16*)&h;
}

// async global->LDS, 16B per lane; LDS dest is wave-uniform base + lane*16
__device__ inline void gll16(const void* g, void* l) {
  __builtin_amdgcn_global_load_lds(
      (const __attribute__((address_space(1))) unsigned int*)g,
      (__attribute__((address_space(3))) unsigned int*)l, 16, 0, 0);
}

// XOR swizzle for [*][64] u16 LDS tiles (manual-write paths)
__device__ inline int swzi(int r, int c) {
  return (r * 64 + c) ^ ((((r & 7) ^ ((r >> 3) & 7))) << 3);
}

// ---- block-wide reduce (exactly 256 threads / 4 waves) ----
__device__ inline float block_reduce(float v, bool is_max, float* buf4) {
  int lane = threadIdx.x & 63, wid = threadIdx.x >> 6;
#pragma unroll
  for (int off = 32; off; off >>= 1) {
    float o = __shfl_down(v, off, 64);
    v = is_max ? fmaxf(v, o) : v + o;
  }
  if (lane == 0) buf4[wid] = v;
  __syncthreads();
  float r = is_max ? fmaxf(fmaxf(buf4[0], buf4[1]), fmaxf(buf4[2], buf4[3]))
                   : buf4[0] + buf4[1] + buf4[2] + buf4[3];
  __syncthreads();
  return r;
}

// ---- x = tok_emb[idx] + pos_emb ----
__global__ __launch_bounds__(256) void k_embed(const int* __restrict__ idx,
                                               const float* __restrict__ tok,
                                               const float* __restrict__ pos,
                                               float* __restrict__ x) {
  int i = blockIdx.x * 256 + threadIdx.x;
  int row = i / D, d = i - row * D;
  int t = row & (T - 1);
  x[i] = tok[(size_t)idx[row] * D + d] + pos[(size_t)t * D + d];
}

// ---- f32 -> bf16 convert, 4 elems/thread ----
__global__ __launch_bounds__(256) void k_cvt(const float* __restrict__ in,
                                             u16* __restrict__ out, int n4) {
  int i = blockIdx.x * 256 + threadIdx.x;
  if (i >= n4) return;
  float4 v = ((const float4*)in)[i];
  ushort4 o;
  o.x = f2b(v.x); o.y = f2b(v.y); o.z = f2b(v.z); o.w = f2b(v.w);
  ((ushort4*)out)[i] = o;
}

// ---- all block weights f32 -> bf16 in one launch (contiguous dest) ----
__global__ __launch_bounds__(256) void k_cvtw(const float* __restrict__ q,
                                              const float* __restrict__ p,
                                              const float* __restrict__ f1,
                                              const float* __restrict__ f2,
                                              u16* __restrict__ out) {
  const int N0 = L * D3 * D / 4, N1 = L * D * D / 4;
  const int N2 = L * F * D / 4, N3 = L * D * F / 4;
  int i = blockIdx.x * 256 + threadIdx.x;
  if (i >= N0 + N1 + N2 + N3) return;
  const float* src;
  int j = i;
  if (i < N0) { src = q; }
  else if (i < N0 + N1) { src = p; j = i - N0; }
  else if (i < N0 + N1 + N2) { src = f1; j = i - N0 - N1; }
  else { src = f2; j = i - N0 - N1 - N2; }
  float4 v = ((const float4*)src)[j];
  ushort4 o;
  o.x = f2b(v.x); o.y = f2b(v.y); o.z = f2b(v.z); o.w = f2b(v.w);
  ((ushort4*)out)[i] = o;
}

// ---- LayerNorm: one WAVE per row of 768, bf16 out; no LDS, no barriers ----
__global__ __launch_bounds__(256) void k_lnorm(const float* __restrict__ x,
                                               const float* __restrict__ w,
                                               const float* __restrict__ b,
                                               u16* __restrict__ out) {
  int lane = threadIdx.x & 63, wid = threadIdx.x >> 6;
  int row = blockIdx.x * 4 + wid;
  const float4* xr = (const float4*)(x + (size_t)row * D);
  float4 v[3];
  float s = 0.f, ss = 0.f;
#pragma unroll
  for (int p = 0; p < 3; ++p) {
    v[p] = xr[lane + 64 * p];
    s += v[p].x + v[p].y + v[p].z + v[p].w;
    ss += v[p].x * v[p].x + v[p].y * v[p].y + v[p].z * v[p].z + v[p].w * v[p].w;
  }
#pragma unroll
  for (int off = 32; off; off >>= 1) {
    s += __shfl_xor(s, off, 64);
    ss += __shfl_xor(ss, off, 64);
  }
  float mu = s * (1.0f / D);
  float var = ss * (1.0f / D) - mu * mu;
  float rs = rsqrtf(var + 1e-5f);
  ushort4* orow = (ushort4*)(out + (size_t)row * D);
#pragma unroll
  for (int p = 0; p < 3; ++p) {
    float4 wv = ((const float4*)w)[lane + 64 * p];
    float4 bv = ((const float4*)b)[lane + 64 * p];
    ushort4 o;
    o.x = f2b((v[p].x - mu) * rs * wv.x + bv.x);
    o.y = f2b((v[p].y - mu) * rs * wv.y + bv.y);
    o.z = f2b((v[p].z - mu) * rs * wv.z + bv.z);
    o.w = f2b((v[p].w - mu) * rs * wv.w + bv.w);
    orow[lane + 64 * p] = o;
  }
}

// ---- fused: x += sum(nparts split-K partials) + bias2; out = LN(x); x updated ----
__global__ __launch_bounds__(256) void k_lncomb(float* __restrict__ x,
                                                const float* __restrict__ parts,
                                                const float* __restrict__ bias2,
                                                const float* __restrict__ w,
                                                const float* __restrict__ b,
                                                u16* __restrict__ out, int nparts) {
  int lane = threadIdx.x & 63, wid = threadIdx.x >> 6;
  int row = blockIdx.x * 4 + wid;
  float4* xr = (float4*)(x + (size_t)row * D);
  float4 v[3];
  float s = 0.f, ss = 0.f;
#pragma unroll
  for (int p = 0; p < 3; ++p) {
    v[p] = xr[lane + 64 * p];
    for (int pp = 0; pp < nparts; ++pp) {
      float4 pv = ((const float4*)(parts + (size_t)pp * M * D + (size_t)row * D))[lane + 64 * p];
      v[p].x += pv.x; v[p].y += pv.y; v[p].z += pv.z; v[p].w += pv.w;
    }
    float4 b2 = ((const float4*)bias2)[lane + 64 * p];
    v[p].x += b2.x; v[p].y += b2.y; v[p].z += b2.z; v[p].w += b2.w;
    s += v[p].x + v[p].y + v[p].z + v[p].w;
    ss += v[p].x * v[p].x + v[p].y * v[p].y + v[p].z * v[p].z + v[p].w * v[p].w;
  }
#pragma unroll
  for (int off = 32; off; off >>= 1) {
    s += __shfl_xor(s, off, 64);
    ss += __shfl_xor(ss, off, 64);
  }
  float mu = s * (1.0f / D);
  float var = ss * (1.0f / D) - mu * mu;
  float rs = rsqrtf(var + 1e-5f);
  ushort4* orow = (ushort4*)(out + (size_t)row * D);
#pragma unroll
  for (int p = 0; p < 3; ++p) {
    xr[lane + 64 * p] = v[p];
    float4 wv = ((const float4*)w)[lane + 64 * p];
    float4 bv = ((const float4*)b)[lane + 64 * p];
    ushort4 o;
    o.x = f2b((v[p].x - mu) * rs * wv.x + bv.x);
    o.y = f2b((v[p].y - mu) * rs * wv.y + bv.y);
    o.z = f2b((v[p].z - mu) * rs * wv.z + bv.z);
    o.w = f2b((v[p].w - mu) * rs * wv.w + bv.w);
    orow[lane + 64 * p] = o;
  }
}

// ---- layer GEMM: C[M,N] = A[M,K] @ W[N,K]^T, 128x128 tile, 8 waves,
//      BK=64 double-buffered, counted vmcnt(4) pipeline, swizzled LDS ----
// flags: 1=bias, 2=residual add (f32), 4=exact gelu, 8=bf16 output,
//        16=split-K partial (f32 out, no bias/resid; K-range = blockIdx.z)
__global__ __launch_bounds__(512, 2) void k_gemm8(
    const u16* __restrict__ A, const u16* __restrict__ W,
    const float* __restrict__ bias, const float* __restrict__ resid,
    void* __restrict__ Cout, int kLen, int kStride, int ldC, int flags) {
  __shared__ __attribute__((aligned(16))) u16 lds[2][2][128 * 64];
  int tid = threadIdx.x, w = tid >> 6, lane = tid & 63;
  int wm = w >> 2, wn = w & 3;
  int bn = blockIdx.x, bm = blockIdx.y;
  int frow = lane & 15, g = lane >> 4;
  int sr = lane >> 3, scu = lane & 7;
  int kz = (flags & 16) ? blockIdx.z * kLen : 0;
  const u16* Ab = A + (size_t)bm * 128 * kStride + kz;
  const u16* Wb = W + (size_t)bn * 128 * kStride + kz;
  float* Cp = (float*)Cout + ((flags & 16) ? (size_t)blockIdx.z * M * (size_t)ldC : 0);
  int NT = kLen >> 6;

  f32x4 acc[4][2];
#pragma unroll
  for (int i = 0; i < 4; ++i)
#pragma unroll
    for (int j = 0; j < 2; ++j) acc[i][j] = (f32x4)(0.f);

#define STG(t)                                                            \
  {                                                                       \
    _Pragma("unroll") for (int rr = 0; rr < 2; ++rr) {                    \
      int row = rr * 64 + w * 8 + sr;                                     \
      int gcu = scu ^ (row & 7);                                          \
      gll16(Ab + (size_t)row * kStride + (t) * 64 + gcu * 8,              \
            &lds[(t) & 1][0][(rr * 64 + w * 8) * 64]);                    \
      gll16(Wb + (size_t)row * kStride + (t) * 64 + gcu * 8,              \
            &lds[(t) & 1][1][(rr * 64 + w * 8) * 64]);                    \
    }                                                                     \
  }

  STG(0);
  asm volatile("s_waitcnt vmcnt(0)");
  __builtin_amdgcn_s_barrier();

  for (int t = 0; t < NT; ++t) {
    if (t + 1 < NT) {
      STG(t + 1);                          // next tile into other buffer
      asm volatile("s_waitcnt vmcnt(4)");  // tile t landed; t+1 stays in flight
    } else {
      asm volatile("s_waitcnt vmcnt(0)");
    }
    __builtin_amdgcn_s_barrier();
    const u16* bA = &lds[t & 1][0][0];
    const u16* bB = &lds[t & 1][1][0];
    bf16x8 ar[8], br[4];
#pragma unroll
    for (int i = 0; i < 4; ++i)
#pragma unroll
      for (int kk = 0; kk < 2; ++kk) {
        int r = wm * 64 + i * 16 + frow;
        ar[i * 2 + kk] = *(const bf16x8*)(bA + r * 64 + ((g + kk * 4) ^ (r & 7)) * 8);
      }
#pragma unroll
    for (int j = 0; j < 2; ++j)
#pragma unroll
      for (int kk = 0; kk < 2; ++kk) {
        int r = wn * 32 + j * 16 + frow;
        br[j * 2 + kk] = *(const bf16x8*)(bB + r * 64 + ((g + kk * 4) ^ (r & 7)) * 8);
      }
    __builtin_amdgcn_s_setprio(1);
#pragma unroll
    for (int i = 0; i < 4; ++i)
#pragma unroll
      for (int j = 0; j < 2; ++j)
#pragma unroll
        for (int kk = 0; kk < 2; ++kk)
          acc[i][j] = __builtin_amdgcn_mfma_f32_16x16x32_bf16(
              ar[i * 2 + kk], br[j * 2 + kk], acc[i][j], 0, 0, 0);
    __builtin_amdgcn_s_setprio(0);
    __builtin_amdgcn_s_barrier();  // reads of buf[t] done before overwrite
  }
#undef STG

  int m0 = bm * 128 + wm * 64 + g * 4;
  int n0 = bn * 128 + wn * 32 + frow;
#pragma unroll
  for (int i = 0; i < 4; ++i) {
#pragma unroll
    for (int j = 0; j < 2; ++j) {
      int n = n0 + j * 16;
      float bv = (flags & 1) ? bias[n] : 0.f;
#pragma unroll
      for (int q = 0; q < 4; ++q) {
        int m = m0 + i * 16 + q;
        size_t off = (size_t)m * ldC + n;
        float v = acc[i][j][q] + bv;
        if (flags & 4) v = 0.5f * v * (1.0f + erff(v * 0.70710678118f));
        if (flags & 2) v += resid[off];
        if (flags & 8) ((u16*)Cout)[off] = f2b(v);
        else           Cp[off] = v;
      }
    }
  }
}

// ---- lm_head 256x256 GEMM, K=768 fixed, 8 waves, dbuf + 4-phase + fused LSE.
// Round-14 proven schedule (308 us): next-tile stages in phases A/B, single
// vmcnt(0) drain at phase D. FROZEN — 3 restructurings all regressed.
__global__ __launch_bounds__(512, 2) void k_lm256(
    const u16* __restrict__ A, const u16* __restrict__ B,
    float* __restrict__ C, float* __restrict__ pm, float* __restrict__ ps,
    int gc0) {
  __shared__ __attribute__((aligned(16))) u16 lds[2][2][2][128 * 64];
  __shared__ float pml[256][4], psl[256][4];
  const int K = 768, NT = 12;
  int tid = threadIdx.x, w = tid >> 6, lane = tid & 63;
  int wm = w >> 2, wn = w & 3;
  int bm = blockIdx.y, bn = blockIdx.x;
  int frow = lane & 15, g = lane >> 4;
  int sr = lane >> 3, scu = lane & 7;
  const u16* Abase = A + (size_t)bm * 256 * K;
  const u16* Bbase = B + (size_t)bn * 256 * K;

  f32x4 acc[8][4];
#pragma unroll
  for (int i = 0; i < 8; ++i)
#pragma unroll
    for (int j = 0; j < 4; ++j) acc[i][j] = (f32x4)(0.f);

#define STAGE(t, h)                                                       \
  {                                                                       \
    const u16* src = ((h) < 2 ? Abase : Bbase) + (size_t)(((h)&1) * 128) * K; \
    u16* dst = &lds[(t) & 1][(h) >> 1][(h)&1][0];                         \
    _Pragma("unroll") for (int rr = 0; rr < 2; ++rr) {                    \
      int row = rr * 64 + w * 8 + sr;                                     \
      int gcu = scu ^ (row & 7);                                          \
      gll16(src + (size_t)row * K + (t) * 64 + gcu * 8,                   \
            dst + (rr * 64 + w * 8) * 64);                                \
    }                                                                     \
  }

  bf16x8 ar[8], br[8];
#define LDA(T_, ILO)                                                      \
  {                                                                       \
    const u16* base = &lds[(T_)&1][0][wm][0];                             \
    _Pragma("unroll") for (int ii = 0; ii < 4; ++ii)                      \
    _Pragma("unroll") for (int kk = 0; kk < 2; ++kk) {                    \
      int ri = ((ILO) + ii) * 16 + frow;                                  \
      int u = (g + kk * 4) ^ (ri & 7);                                    \
      ar[ii * 2 + kk] = *(const bf16x8*)(base + ri * 64 + u * 8);         \
    }                                                                     \
  }
#define LDB(T_, JLO, BO)                                                  \
  {                                                                       \
    const u16* base = &lds[(T_)&1][1][wn >> 1][0];                        \
    _Pragma("unroll") for (int jj = 0; jj < 2; ++jj)                      \
    _Pragma("unroll") for (int kk = 0; kk < 2; ++kk) {                    \
      int rj = (wn & 1) * 64 + ((JLO) + jj) * 16 + frow;                  \
      int u = (g + kk * 4) ^ (rj & 7);                                    \
      br[(BO) + jj * 2 + kk] = *(const bf16x8*)(base + rj * 64 + u * 8);  \
    }                                                                     \
  }
#define MFMA16(ILO, JLO, BO)                                              \
  _Pragma("unroll") for (int ii = 0; ii < 4; ++ii)                        \
  _Pragma("unroll") for (int jj = 0; jj < 2; ++jj)                        \
  _Pragma("unroll") for (int kk = 0; kk < 2; ++kk)                        \
    acc[(ILO) + ii][(JLO) + jj] = __builtin_amdgcn_mfma_f32_16x16x32_bf16( \
        ar[ii * 2 + kk], br[(BO) + jj * 2 + kk], acc[(ILO) + ii][(JLO) + jj], 0, 0, 0);

  STAGE(0, 0); STAGE(0, 1); STAGE(0, 2); STAGE(0, 3);
  asm volatile("s_waitcnt vmcnt(0)");
  __builtin_amdgcn_s_barrier();

  for (int t = 0; t < NT; ++t) {
    bool pf = (t + 1 < NT);
    LDA(t, 0); LDB(t, 0, 0);
    if (pf) { STAGE(t + 1, 0); STAGE(t + 1, 1); }
    __builtin_amdgcn_s_setprio(1);
    MFMA16(0, 0, 0);
    __builtin_amdgcn_s_setprio(0);
    __builtin_amdgcn_s_barrier();
    LDB(t, 2, 4);
    if (pf) { STAGE(t + 1, 2); STAGE(t + 1, 3); }
    __builtin_amdgcn_s_setprio(1);
    MFMA16(0, 2, 4);
    __builtin_amdgcn_s_setprio(0);
    __builtin_amdgcn_s_barrier();
    LDA(t, 4);
    __builtin_amdgcn_s_setprio(1);
    MFMA16(4, 2, 4);
    __builtin_amdgcn_s_setprio(0);
    __builtin_amdgcn_s_barrier();
    __builtin_amdgcn_s_setprio(1);
    MFMA16(4, 0, 0);
    __builtin_amdgcn_s_setprio(0);
    asm volatile("s_waitcnt vmcnt(0)");
    __builtin_amdgcn_s_barrier();
  }

#pragma unroll
  for (int ii = 0; ii < 8; ++ii) {
#pragma unroll
    for (int q = 0; q < 4; ++q) {
      float mx = fmaxf(fmaxf(acc[ii][0][q], acc[ii][1][q]),
                       fmaxf(acc[ii][2][q], acc[ii][3][q]));
      mx = fmaxf(mx, __shfl_xor(mx, 1, 64));
      mx = fmaxf(mx, __shfl_xor(mx, 2, 64));
      mx = fmaxf(mx, __shfl_xor(mx, 4, 64));
      mx = fmaxf(mx, __shfl_xor(mx, 8, 64));
      float sm = 0.f;
#pragma unroll
      for (int jj = 0; jj < 4; ++jj) sm += __expf(acc[ii][jj][q] - mx);
      sm += __shfl_xor(sm, 1, 64);
      sm += __shfl_xor(sm, 2, 64);
      sm += __shfl_xor(sm, 4, 64);
      sm += __shfl_xor(sm, 8, 64);
      int lrow = wm * 128 + ii * 16 + g * 4 + q;
      if (frow == 0) { pml[lrow][wn] = mx; psl[lrow][wn] = sm; }
      size_t off = (size_t)(bm * 256 + lrow) * V + gc0 + bn * 256 + wn * 64 + frow;
#pragma unroll
      for (int jj = 0; jj < 4; ++jj) C[off + jj * 16] = acc[ii][jj][q];
    }
  }
  __syncthreads();
  if (tid < 256) {
    float m = fmaxf(fmaxf(pml[tid][0], pml[tid][1]), fmaxf(pml[tid][2], pml[tid][3]));
    float s = 0.f;
#pragma unroll
    for (int w4 = 0; w4 < 4; ++w4) s += psl[tid][w4] * __expf(pml[tid][w4] - m);
    size_t grow = bm * 256 + tid;
    int pb = gc0 / 256 + bn;
    pm[grow * PBT + pb] = m;
    ps[grow * PBT + pb] = s;
  }
#undef STAGE
#undef LDA
#undef LDB
#undef MFMA16
}

// ---- MFMA flash attention, balanced + 8-wave parallel pair + Q-hoist ----
// Q fragments are loop-invariant: loaded once from global into registers
// (swizzle algebra collapses to plain Q[row][g*8..]); lQ LDS buffer removed
// (48->32 KB/block).
__global__ __launch_bounds__(512) void k_fattn(const u16* __restrict__ qkv,
                                               u16* __restrict__ y) {
  __shared__ __attribute__((aligned(16))) u16 lK[64 * 64];
  __shared__ __attribute__((aligned(16))) u16 lVt[64 * 64];
  __shared__ __attribute__((aligned(16))) u16 lP[128 * 64];
  int tid = threadIdx.x;
  int w = tid >> 6, lane = tid & 63;
  int tq = w >> 2, ws4 = w & 3;
  int xi = blockIdx.x;
  int bh = blockIdx.y, b = bh / H, h = bh - b * H;
  int myqt = tq ? xi : (15 - xi);
  const u16* base = qkv + (size_t)b * T * D3 + h * DH;
  int srow = lane >> 3;
  int scu = lane & 7;
  int frow = lane & 15, g = lane >> 4;
  int s16 = ws4 * 16;
  int qrow = g * 4;
  int f7 = frow & 7;

  // Q-hoist: this lane's two Q fragments, loaded once (loop-invariant)
  int qgrow = myqt * 64 + s16 + frow;
  bf16x8 aq0 = *(const bf16x8*)(base + (size_t)qgrow * D3 + g * 8);
  bf16x8 aq1 = *(const bf16x8*)(base + (size_t)qgrow * D3 + 32 + g * 8);

  float m_r[4], l_r[4];
  f32x4 o[4];
#pragma unroll
  for (int i = 0; i < 4; ++i) { m_r[i] = -1e30f; l_r[i] = 0.f; o[i] = (f32x4)(0.f); }

  int ktmax = 15 - xi;
  int kvrow = w * 8 + srow;
  uint4 kr = *(const uint4*)(base + D + (size_t)kvrow * D3 + scu * 8);
  uint4 vr = *(const uint4*)(base + 2 * D + (size_t)kvrow * D3 + scu * 8);

  for (int kt = 0; kt <= ktmax; ++kt) {
    __syncthreads();  // prev-iter LDS reads done
    int k0 = kt * 64;
    *(uint4*)(lK + kvrow * 64 + (scu ^ (kvrow & 7)) * 8) = kr;
    {
      unsigned vals[4] = {vr.x, vr.y, vr.z, vr.w};
#pragma unroll
      for (int e = 0; e < 4; ++e) {
        lVt[swzi(scu * 8 + 2 * e, kvrow)]     = (u16)(vals[e] & 0xffff);
        lVt[swzi(scu * 8 + 2 * e + 1, kvrow)] = (u16)(vals[e] >> 16);
      }
    }
    __syncthreads();
    if (kt < ktmax) {
      int rown = k0 + 64 + kvrow;
      kr = *(const uint4*)(base + D + (size_t)rown * D3 + scu * 8);
      vr = *(const uint4*)(base + 2 * D + (size_t)rown * D3 + scu * 8);
    }

    if (tq == 0 || kt <= xi) {
      bool diag = (kt == myqt);
      f32x4 sv[4];
#pragma unroll
      for (int kn = 0; kn < 4; ++kn) {
        bf16x8 bk0 = *(const bf16x8*)(lK + (kn * 16 + frow) * 64 + (g ^ f7) * 8);
        bf16x8 bk1 = *(const bf16x8*)(lK + (kn * 16 + frow) * 64 + ((g + 4) ^ f7) * 8);
        sv[kn] = __builtin_amdgcn_mfma_f32_16x16x32_bf16(aq0, bk0, (f32x4)(0.f), 0, 0, 0);
        sv[kn] = __builtin_amdgcn_mfma_f32_16x16x32_bf16(aq1, bk1, sv[kn], 0, 0, 0);
      }
#pragma unroll
      for (int kn = 0; kn < 4; ++kn)
#pragma unroll
        for (int qi = 0; qi < 4; ++qi) {
          float v = sv[kn][qi] * SCALE;
          if (diag) {
            int qg = myqt * 64 + s16 + qrow + qi;
            int kg = k0 + kn * 16 + frow;
            if (kg > qg) v = -1e30f;
          }
          sv[kn][qi] = v;
        }
#pragma unroll
      for (int qi = 0; qi < 4; ++qi) {
        float rm = fmaxf(fmaxf(sv[0][qi], sv[1][qi]), fmaxf(sv[2][qi], sv[3][qi]));
        rm = fmaxf(rm, __shfl_xor(rm, 1, 64));
        rm = fmaxf(rm, __shfl_xor(rm, 2, 64));
        rm = fmaxf(rm, __shfl_xor(rm, 4, 64));
        rm = fmaxf(rm, __shfl_xor(rm, 8, 64));
        float mn = fmaxf(m_r[qi], rm);
        float alpha = __expf(m_r[qi] - mn);
        m_r[qi] = mn;
        float rs = 0.f;
#pragma unroll
        for (int kn = 0; kn < 4; ++kn) {
          float p = __expf(sv[kn][qi] - mn);
          sv[kn][qi] = p;
          rs += p;
        }
        rs += __shfl_xor(rs, 1, 64);
        rs += __shfl_xor(rs, 2, 64);
        rs += __shfl_xor(rs, 4, 64);
        rs += __shfl_xor(rs, 8, 64);
        l_r[qi] = l_r[qi] * alpha + rs;
#pragma unroll
        for (int df = 0; df < 4; ++df) o[df][qi] *= alpha;
      }
#pragma unroll
      for (int kn = 0; kn < 4; ++kn)
#pragma unroll
        for (int qi = 0; qi < 4; ++qi)
          lP[swzi(w * 16 + qrow + qi, kn * 16 + frow)] = f2b(sv[kn][qi]);
      bf16x8 pa0 = *(const bf16x8*)(lP + swzi(w * 16 + frow, g * 8));
      bf16x8 pa1 = *(const bf16x8*)(lP + swzi(w * 16 + frow, 32 + g * 8));
#pragma unroll
      for (int df = 0; df < 4; ++df) {
        bf16x8 bv0 = *(const bf16x8*)(lVt + swzi(df * 16 + frow, g * 8));
        bf16x8 bv1 = *(const bf16x8*)(lVt + swzi(df * 16 + frow, 32 + g * 8));
        o[df] = __builtin_amdgcn_mfma_f32_16x16x32_bf16(pa0, bv0, o[df], 0, 0, 0);
        o[df] = __builtin_amdgcn_mfma_f32_16x16x32_bf16(pa1, bv1, o[df], 0, 0, 0);
      }
    }
  }

#pragma unroll
  for (int df = 0; df < 4; ++df)
#pragma unroll
    for (int qi = 0; qi < 4; ++qi) {
      int qg = myqt * 64 + s16 + qrow + qi;
      y[(size_t)(b * T + qg) * D + h * DH + df * 16 + frow] =
          f2b(o[df][qi] / l_r[qi]);
    }
}

// ---- final LSE + NLL from partials; one wave per row ----
__global__ __launch_bounds__(256) void k_loss_rows(
    const float* __restrict__ pm, const float* __restrict__ ps,
    const float* __restrict__ logits, const int* __restrict__ targets,
    float* __restrict__ nll) {
  int lane = threadIdx.x & 63, wid = threadIdx.x >> 6;
  int row = blockIdx.x * 4 + wid;
  const float* pmr = pm + (size_t)row * PBT;
  const float* psr = ps + (size_t)row * PBT;
  float m = -1e30f;
  for (int i = lane; i < PBT; i += 64) m = fmaxf(m, pmr[i]);
#pragma unroll
  for (int off = 32; off; off >>= 1) m = fmaxf(m, __shfl_xor(m, off, 64));
  float s = 0.f;
  for (int i = lane; i < PBT; i += 64) s += psr[i] * __expf(pmr[i] - m);
#pragma unroll
  for (int off = 32; off; off >>= 1) s += __shfl_xor(s, off, 64);
  if (lane == 0) {
    int tgt = targets[row];
    nll[row] = (tgt != -100) ? (m + logf(s) - logits[(size_t)row * V + tgt]) : 0.f;
  }
}

__global__ __launch_bounds__(256) void k_loss_final(const float* __restrict__ nll,
                                                    const int* __restrict__ targets,
                                                    float* __restrict__ out) {
  __shared__ float buf4[4];
  float s = 0.f, c = 0.f;
  for (int i = threadIdx.x; i < M; i += 256) {
    s += nll[i];
    c += (targets[i] != -100) ? 1.f : 0.f;
  }
  s = block_reduce(s, false, buf4);
  c = block_reduce(c, false, buf4);
  if (threadIdx.x == 0) out[0] = s / fmaxf(c, 1.f);
}

extern "C" void kernel_launch(void* const* d_in, const int* in_sizes, int n_in,
                              void* d_out, int out_size, void* d_ws, size_t ws_size,
                              hipStream_t stream) {
  const int* idx       = (const int*)d_in[0];
  const int* targets   = (const int*)d_in[1];
  const float* tok     = (const float*)d_in[2];
  const float* pos     = (const float*)d_in[3];
  const float* qkv_w   = (const float*)d_in[4];
  const float* qkv_b   = (const float*)d_in[5];
  const float* proj_w  = (const float*)d_in[6];
  const float* proj_b  = (const float*)d_in[7];
  const float* fc1_w   = (const float*)d_in[8];
  const float* fc1_b   = (const float*)d_in[9];
  const float* fc2_w   = (const float*)d_in[10];
  const float* fc2_b   = (const float*)d_in[11];
  const float* ln1_w   = (const float*)d_in[12];
  const float* ln1_b   = (const float*)d_in[13];
  const float* ln2_w   = (const float*)d_in[14];
  const float* ln2_b   = (const float*)d_in[15];
  const float* lnf_w   = (const float*)d_in[16];
  const float* lnf_b   = (const float*)d_in[17];

  float* logits = (float*)d_out;

  // ---- ws layout ----
  char* ws = (char*)d_ws;
  float* x   = (float*)ws;                  // M*D f32        12.58 MB
  u16* hb    = (u16*)(ws + 12582912);       // M*D bf16        6.29 MB
  u16* yb    = (u16*)(ws + 18874368);       // M*D bf16        6.29 MB
  u16* wb    = (u16*)(ws + 25165824);       // lm_head B bf16 (chunk or full tok)
  bool big = ws_size >= (size_t)(25165824 + 49152000 + 2048000 * 2 + 16384);
  float* pm, * ps, * nll;
  if (big) {
    pm  = (float*)(ws + 25165824 + 49152000);
    ps  = (float*)(ws + 25165824 + 49152000 + 2048000);
    nll = (float*)(ws + 25165824 + 49152000 + 4096000);
  } else {
    pm  = (float*)(ws + 34996224);
    ps  = (float*)(ws + 37044224);
    nll = (float*)(ws + 39092224);
  }

  // ---- d_out scratch (dead before logits are written) ----
  u16* qkvb   = (u16*)logits;                        // M*D3 bf16
  u16* f1b    = (u16*)(logits + 9437184);            // M*F bf16
  u16* wqkv   = (u16*)(logits + 15728640);           // contiguous weights (ends ~176MB)
  u16* wproj  = (u16*)(logits + 22806528);
  u16* wfc1   = (u16*)(logits + 25165824);
  u16* wfc2   = (u16*)(logits + 34603008);
  float* fc2p = (float*)((char*)logits + 201326592); // 4x M*D f32 split-K partials

  {
    const int NW4 = (L * D3 * D + L * D * D + L * F * D + L * D * F) / 4;
    k_cvtw<<<(NW4 + 255) / 256, 256, 0, stream>>>(qkv_w, proj_w, fc1_w, fc2_w, wqkv);
  }

  k_embed<<<(M * D) / 256, 256, 0, stream>>>(idx, tok, pos, x);

  for (int l = 0; l < L; ++l) {
    if (l == 0)
      k_lnorm<<<M / 4, 256, 0, stream>>>(x, ln1_w, ln1_b, hb);
    else
      k_lncomb<<<M / 4, 256, 0, stream>>>(x, fc2p, fc2_b + (size_t)(l - 1) * D,
                                          ln1_w + (size_t)l * D, ln1_b + (size_t)l * D, hb, 4);
    k_gemm8<<<dim3(D3 / 128, M / 128), 512, 0, stream>>>(
        hb, wqkv + (size_t)l * D3 * D, qkv_b + (size_t)l * D3, nullptr, qkvb, D, D, D3, 9);
    k_fattn<<<dim3(8, BATCH * H), 512, 0, stream>>>(qkvb, yb);
    // proj split-K=2: partials only; combine + residual fused into ln2
    k_gemm8<<<dim3(D / 128, M / 128, 2), 512, 0, stream>>>(
        yb, wproj + (size_t)l * D * D, nullptr, nullptr, fc2p, 384, D, D, 16);
    k_lncomb<<<M / 4, 256, 0, stream>>>(x, fc2p, proj_b + (size_t)l * D,
                                        ln2_w + (size_t)l * D, ln2_b + (size_t)l * D, hb, 2);
    k_gemm8<<<dim3(F / 128, M / 128), 512, 0, stream>>>(
        hb, wfc1 + (size_t)l * F * D, fc1_b + (size_t)l * F, nullptr, f1b, D, D, F, 13);
    // fc2 split-K=4: partials only; combine fused into next LN
    k_gemm8<<<dim3(D / 128, M / 128, 4), 512, 0, stream>>>(
        f1b, wfc2 + (size_t)l * D * F, nullptr, nullptr, fc2p, 768, F, D, 16);
  }

  k_lncomb<<<M / 4, 256, 0, stream>>>(x, fc2p, fc2_b + (size_t)(L - 1) * D,
                                      lnf_w, lnf_b, hb, 4);
  if (big) {
    k_cvt<<<(V * D / 4 + 255) / 256, 256, 0, stream>>>(tok, wb, V * D / 4);
    k_lm256<<<dim3(V / 256, M / 256), 512, 0, stream>>>(
        hb, wb, logits, pm, ps, 0);
  } else {
    for (int c = 0; c < 5; ++c) {
      k_cvt<<<(VCHUNK * D / 4 + 255) / 256, 256, 0, stream>>>(
          tok + (size_t)c * VCHUNK * D, wb, VCHUNK * D / 4);
      k_lm256<<<dim3(VCHUNK / 256, M / 256), 512, 0, stream>>>(
          hb, wb, logits, pm, ps, c * VCHUNK);
    }
  }
  k_loss_rows<<<M / 4, 256, 0, stream>>>(pm, ps, logits, targets, nll);
  k_loss_final<<<1, 256, 0, stream>>>(nll, targets, logits + (size_t)M * V);
}